// Round 10
// baseline (2351.305 us; speedup 1.0000x reference)
//
#include <hip/hip_runtime.h>
#include <hip/hip_bf16.h>

// BiLSTM-CRF forward. B=64, L=1024, E=256, H=128 (per dir), C=5, V=32000.
// R9: (1) LSTM per-step barrier is LDS-only (fence local + s_barrier + fence
// local -> s_waitcnt lgkmcnt(0); s_barrier, NO vmcnt drain) so the depth-2
// G/s prefetch actually stays in flight across steps. (2) Weight columns
// permuted jp = dir*512 + (u>>5)*128 + g*32 + (u&31) so each GEMM N-block
// covers all 4 gates of 32 units -> G stores are dense 8 B/thread (write amp
// 4x -> 1x). G layout [grp][l][tid][4] (LSTM: one dwordx2/step, depth-2 dbuf).

typedef unsigned short u16;
typedef unsigned int u32;
typedef __bf16 v8bf __attribute__((ext_vector_type(8)));
typedef float  v4f  __attribute__((ext_vector_type(4)));
typedef unsigned short u16x8 __attribute__((ext_vector_type(8)));
typedef unsigned short u16x4 __attribute__((ext_vector_type(4)));

__device__ __forceinline__ float b2f(u16 b){
  return __builtin_bit_cast(float, ((unsigned)b) << 16);
}
__device__ __forceinline__ u16 f2b(float x){           // RNE f32->bf16
  unsigned u = __builtin_bit_cast(unsigned, x);
  unsigned r = (u + 0x7FFFu + ((u >> 16) & 1u)) >> 16;
  return (u16)r;
}
__device__ __forceinline__ float xor8(float x){        // lane <- lane^8 (row_ror:8)
  int t = __builtin_amdgcn_mov_dpp(__builtin_bit_cast(int, x), 0x128, 0xF, 0xF, true);
  return __builtin_bit_cast(float, t);
}
// LDS-only workgroup barrier: orders LDS, leaves global loads/stores in flight.
__device__ __forceinline__ void lds_only_barrier(){
  __builtin_amdgcn_fence(__ATOMIC_RELEASE, "workgroup", "local");
  __builtin_amdgcn_s_barrier();
  __builtin_amdgcn_fence(__ATOMIC_ACQUIRE, "workgroup", "local");
}

// ---------------- weight prep: permuted concat + fp32->bf16 ----------------
// permuted col jp: dirj=jp>>9, ub=(jp>>7)&3, g=(jp>>5)&3, ul=jp&31; u=ub*32+ul
// original row within dir: r = g*128 + u
__global__ __launch_bounds__(256) void conv_weights(
    const float* __restrict__ Wih1f, const float* __restrict__ Wih1b,
    const float* __restrict__ bih1f, const float* __restrict__ bhh1f,
    const float* __restrict__ bih1b, const float* __restrict__ bhh1b,
    const float* __restrict__ Wih2f, const float* __restrict__ Wih2b,
    const float* __restrict__ bih2f, const float* __restrict__ bhh2f,
    const float* __restrict__ bih2b, const float* __restrict__ bhh2b,
    u16* __restrict__ W1cat, u16* __restrict__ WAcat,
    float* __restrict__ b1cat, float* __restrict__ b2cat)
{
  int gid = blockIdx.x * 256 + threadIdx.x;   // 1024*256 = 262144
  int j = gid >> 8, e = gid & 255;            // j = permuted column jp
  int dirj = j >> 9, ub = (j >> 7) & 3, g = (j >> 5) & 3, ul = j & 31;
  int r = g*128 + ub*32 + ul;                 // 0..511
  float w1 = dirj ? Wih1b[r*256 + e] : Wih1f[r*256 + e];
  float wa = dirj ? Wih2b[(long)r*512 + e] : Wih2f[(long)r*512 + e];  // cols 0..255
  W1cat[gid] = f2b(w1);
  WAcat[gid] = f2b(wa);
  if (e == 0){
    b1cat[j] = dirj ? (bih1b[r] + bhh1b[r]) : (bih1f[r] + bhh1f[r]);
    b2cat[j] = dirj ? (bih2b[r] + bhh2b[r]) : (bih2f[r] + bhh2f[r]);
  }
}

// ---------------- embedding gather (flat order == reshape(L,B,E)) ----------------
__global__ __launch_bounds__(256) void embed_gather(
    const int* __restrict__ sent, const float* __restrict__ emb, u16* __restrict__ X)
{
  int w = threadIdx.x >> 6, lane = threadIdx.x & 63;
  long i = (long)blockIdx.x * 4 + w;          // row of X, 0..65535
  int idx = sent[i];
  const float4* src = (const float4*)(emb + (long)idx * 256);
  float4 v = src[lane];
  u16x4 o; o[0] = f2b(v.x); o[1] = f2b(v.y); o[2] = f2b(v.z); o[3] = f2b(v.w);
  *(u16x4*)(X + i*256 + lane*4) = o;
}

// ---- bf16 MFMA GEMM, A[MxK] rm, Bperm[NxK] rm, +bias; writes G''[grp][l][thr][4] ----
// permuted col j: dirj=j>>9, ub=(j>>7)&3, g=(j>>5)&3, ul=j&31; u=ub*32+ul
// v=u>>3, qd=(u>>1)&3, tb=u&1; grp=dirj*8+(b>>3); thr=v*64+qd*16+tb*8+(b&7); z=g
__global__ __launch_bounds__(256) void gemm_bt(
    const u16* __restrict__ A, const u16* __restrict__ Bm,
    const float* __restrict__ bias, u16* __restrict__ Gp,
    int M, int N, int K)
{
  __shared__ __align__(16) u16 As[128*64];
  __shared__ __align__(16) u16 Bs[128*64];
  int tid = threadIdx.x;
  int w = tid >> 6, lane = tid & 63;
  int lq = lane & 15, quad = lane >> 4;
  int wm = w & 1, wn = w >> 1;
  long m0 = (long)blockIdx.x * 128;
  int n0 = blockIdx.y * 128;
  v4f acc[4][4];
  v4f zero = {0.f, 0.f, 0.f, 0.f};
#pragma unroll
  for (int i=0;i<4;i++)
#pragma unroll
    for (int j=0;j<4;j++) acc[i][j] = zero;

  for (int k0 = 0; k0 < K; k0 += 64){
#pragma unroll
    for (int c = 0; c < 4; c++){
      int lin = c*256 + tid;
      int row = lin >> 3, chunk = lin & 7;            // 128 rows x 8 chunks(16B)
      u16x8 av = *(const u16x8*)(A + (m0+row)*K + k0 + chunk*8);
      u16x8 bv = *(const u16x8*)(Bm + ((long)(n0+row))*K + k0 + chunk*8);
      int sw = chunk ^ (row & 7);                     // XOR swizzle vs bank conflicts
      *(u16x8*)(As + row*64 + sw*8) = av;
      *(u16x8*)(Bs + row*64 + sw*8) = bv;
    }
    __syncthreads();
#pragma unroll
    for (int s = 0; s < 2; s++){
      v8bf af[4], bf_[4];
#pragma unroll
      for (int i=0;i<4;i++){
        int row = wm*64 + i*16 + lq;
        int ch  = (s*4 + quad) ^ (row & 7);
        af[i] = __builtin_bit_cast(v8bf, *(const u16x8*)(As + row*64 + ch*8));
      }
#pragma unroll
      for (int j=0;j<4;j++){
        int row = wn*64 + j*16 + lq;
        int ch  = (s*4 + quad) ^ (row & 7);
        bf_[j] = __builtin_bit_cast(v8bf, *(const u16x8*)(Bs + row*64 + ch*8));
      }
#pragma unroll
      for (int i=0;i<4;i++)
#pragma unroll
        for (int j=0;j<4;j++)
          acc[i][j] = __builtin_amdgcn_mfma_f32_16x16x32_bf16(af[i], bf_[j], acc[i][j], 0, 0, 0);
    }
    __syncthreads();
  }
#pragma unroll
  for (int jt=0;jt<4;jt++){
    int j = n0 + wn*64 + jt*16 + lq;          // permuted column
    float bv = bias[j];
    int dirj = j >> 9, ub = (j >> 7) & 3, g = (j >> 5) & 3, ul = j & 31;
    int u = ub*32 + ul;
    int v_ = u >> 3, qd = (u >> 1) & 3, tb = u & 1;
    int tidl = v_*64 + qd*16 + tb*8;
#pragma unroll
    for (int i16=0;i16<4;i16++){
#pragma unroll
      for (int r2=0;r2<4;r2++){
        long i = m0 + wm*64 + i16*16 + quad*4 + r2;
        int bb = (int)(i & 63); long l = i >> 6;
        long off = ((long)(dirj*8 + (bb>>3)) << 22) + (l << 12)
                 + (long)(tidl + (bb&7))*4 + g;
        Gp[off] = f2b(acc[i16][jt][r2] + bv);
      }
    }
  }
}

// ---------------- persistent BiLSTM layer: 16 WGs x 1024 thr (2 dirs x 8 bgroups) ----
// Thread (v=tid>>6, quad, lq): owns ONE cell: batch=b0+(lq&7), unit U=v*8+2q+(lq>>3).
// MFMA: A rows = gate(m&3) of unit v*8+tau+2*(m>>2); B cols 0..7 = batches (8-15 pad,
// never consumed -> lanes lq>=8 skip LDS reads, keep zero frags). tau=1 cells pulled
// to lanes lq>=8 via DPP row_ror:8. G'': [grp][l][tid][4], per-step dwordx2, dbuf.
__global__ __launch_bounds__(1024, 4) void lstm_layer(
    const u16* __restrict__ G, const float* __restrict__ WhhF, const float* __restrict__ WhhB,
    const float* __restrict__ h0, const float* __restrict__ c0,
    const float* __restrict__ sT, const float* __restrict__ proj,
    u16* __restrict__ Y, float* __restrict__ catOut)
{
  int blk = blockIdx.x;
  int dir = blk >> 3, bg = blk & 7, b0 = bg * 8;
  int tid = threadIdx.x, v = tid >> 6, lane = tid & 63;
  int quad = lane >> 4, lq = lane & 15;
  int b7 = lq & 7, tb = lq >> 3;
  int U = v*8 + 2*quad + tb;                  // this thread's hidden unit
  int batch = b0 + b7;
  const float* Whh = dir ? WhhB : WhhF;

  __shared__ __align__(16) u16 hbuf[2][1024]; // h[8 batches][128 units], XOR-swizzled

  // A-frags in registers: lane holds A[m=lq][k=ks*32+quad*8+j]
  // tile tau row m: gate = m&3, unit = v*8 + tau + 2*(m>>2)
  v8bf Af[2][4];
  {
    int gate = lq & 3;
#pragma unroll
    for (int tau=0;tau<2;tau++){
      int unit = v*8 + tau + 2*(lq>>2);
      const float* wr = Whh + (long)(gate*128 + unit)*128;
#pragma unroll
      for (int ks=0;ks<4;ks++){
        u16x8 tmp;
#pragma unroll
        for (int jj=0;jj<8;jj++) tmp[jj] = f2b(wr[ks*32 + quad*8 + jj]);
        Af[tau][ks] = __builtin_bit_cast(v8bf, tmp);
      }
    }
  }

  int wOff = b7*128 + ((v ^ b7) * 8) + 2*quad + tb;
  int rOff[4];
#pragma unroll
  for (int ks=0;ks<4;ks++) rOff[ks] = lq*128 + (((ks*4 + quad) ^ lq) * 8);

  float cc = c0[dir*8192 + batch*128 + U];
  u16 h0b = f2b(h0[dir*8192 + batch*128 + U]);
  hbuf[0][wOff] = h0b;

  // attention fold (LSTM2): pr[g] = 64*proj[batch, dir*512 + g*128 + U]
  bool att = (proj != nullptr);
  float pr[4];
  if (att){
#pragma unroll
    for (int g=0;g<4;g++)
      pr[g] = 64.0f * proj[(long)batch*1024 + dir*512 + g*128 + U];
  }

  const u16x4* Gp = (const u16x4*)(G + ((size_t)blk << 22)) + tid;
  long dl = dir ? -1 : 1;
  long l0 = dir ? 1023 : 0;
  u16x4 gbuf[2];
  gbuf[0] = Gp[l0 << 10];
  gbuf[1] = Gp[(l0 + dl) << 10];
  const u16x4* gpf = Gp + ((l0 + 2*dl) << 10);  // runs 2 past end: ws-internal, harmless
  u16* yp = Y + (l0*64 + batch)*256 + dir*128 + U;

  // softmax scalar, depth-2 prefetched like gbuf (LSTM2 only)
  float sv[2] = {0.f, 0.f};
  const float* spf = nullptr;
  if (att){
    const float* sp0 = sT + l0*64 + batch;
    sv[0] = sp0[0];
    sv[1] = sp0[dl*64];
    spf = sp0 + 2*dl*64;                      // runs 2 past end: ws-internal, harmless
  }

  // deferred Y store: step t's h stored at top of step t+1.
  u16 hbPrev = h0b;
  u16* ypPrev = yp;

  u16x8 zz = {0,0,0,0,0,0,0,0};
  v8bf bh[4];
#pragma unroll
  for (int ks=0;ks<4;ks++) bh[ks] = __builtin_bit_cast(v8bf, zz);

  bool low = (tb == 0);
  const float NL2E = -1.4426950408889634f;
  const float N2L2E = -2.8853900817779268f;
  v4f zero4 = {0.f, 0.f, 0.f, 0.f};
  __syncthreads();   // full barrier once before the loop (h0 writes + init)

#pragma unroll 2
  for (int it = 0; it < 1024; ++it){
    int slot = it & 1;
    // deferred Y store of previous step's h (first iter: h0 -> overwritten later)
    *ypPrev = hbPrev;
    // gates for this step
    float gc[4];
#pragma unroll
    for (int g=0; g<4; g++) gc[g] = b2f(gbuf[slot][g]);
    gbuf[slot] = *gpf;                        // prefetch it+2 (same parity slot)
    gpf += dl << 10;
    float s = 0.f;
    if (att){
      s = sv[slot];
      sv[slot] = *spf;
      spf += dl*64;
    }
    // h fragments (real cols only)
    if (lq < 8){
#pragma unroll
      for (int ks=0;ks<4;ks++)
        bh[ks] = __builtin_bit_cast(v8bf, *(const u16x8*)(&hbuf[slot][rOff[ks]]));
    }
    // 2x2 MFMA tree per tau (chain depth 2)
    v4f aA0 = __builtin_amdgcn_mfma_f32_16x16x32_bf16(Af[0][0], bh[0], zero4, 0,0,0);
    v4f aB0 = __builtin_amdgcn_mfma_f32_16x16x32_bf16(Af[0][2], bh[2], zero4, 0,0,0);
    v4f aA1 = __builtin_amdgcn_mfma_f32_16x16x32_bf16(Af[1][0], bh[0], zero4, 0,0,0);
    v4f aB1 = __builtin_amdgcn_mfma_f32_16x16x32_bf16(Af[1][2], bh[2], zero4, 0,0,0);
    aA0 = __builtin_amdgcn_mfma_f32_16x16x32_bf16(Af[0][1], bh[1], aA0, 0,0,0);
    aB0 = __builtin_amdgcn_mfma_f32_16x16x32_bf16(Af[0][3], bh[3], aB0, 0,0,0);
    aA1 = __builtin_amdgcn_mfma_f32_16x16x32_bf16(Af[1][1], bh[1], aA1, 0,0,0);
    aB1 = __builtin_amdgcn_mfma_f32_16x16x32_bf16(Af[1][3], bh[3], aB1, 0,0,0);

    float val[4];
#pragma unroll
    for (int r=0;r<4;r++){
      float a0 = aA0[r] + aB0[r];
      float a1 = xor8(aA1[r] + aB1[r]);
      val[r] = (low ? a0 : a1) + gc[r];
    }
    if (att){
#pragma unroll
      for (int r=0;r<4;r++) val[r] = fmaf(s, pr[r], val[r]);
    }

    float i_ = val[0], f_ = val[1], g_ = val[2], o_ = val[3];
    float ef = __builtin_amdgcn_exp2f(f_ * NL2E);
    float ei = __builtin_amdgcn_exp2f(i_ * NL2E);
    float eg = __builtin_amdgcn_exp2f(fminf(g_ * N2L2E, 115.0f));
    float sf = __builtin_amdgcn_rcpf(1.0f + ef);
    float pp = (1.0f - eg) * __builtin_amdgcn_rcpf((1.0f + ei) * (1.0f + eg));
    float c2 = fmaf(cc, sf, pp);
    cc = c2;
    float eo = __builtin_amdgcn_exp2f(o_ * NL2E);
    float ec = __builtin_amdgcn_exp2f(fminf(c2 * N2L2E, 115.0f));
    float hv = (1.0f - ec) * __builtin_amdgcn_rcpf((1.0f + eo) * (1.0f + ec));

    u16 hb = f2b(hv);
    hbuf[slot^1][wOff] = hb;
    hbPrev = hb;
    ypPrev = yp;
    yp += dl*16384;
    lds_only_barrier();   // LDS ordering only; G/s/Y vmem stays in flight
  }
  *ypPrev = hbPrev;                           // last step's h
  if (catOut)
    catOut[(long)batch*256 + dir*128 + U] = cc;
}

// ---------------- attention: e = fbout . catc, softmax over L, proj = catc @ Wih2[:,256:].T ----
// s written TRANSPOSED: sT[l*64 + b]. proj in ORIGINAL column order.
__global__ __launch_bounds__(256) void attn_kernel(
    const u16* __restrict__ y1, const float* __restrict__ catc,
    const float* __restrict__ Wih2f, const float* __restrict__ Wih2b,
    float* __restrict__ sT, float* __restrict__ proj)
{
  int b = blockIdx.x, t = threadIdx.x;
  __shared__ float catv[256];
  __shared__ float ev[1024];
  __shared__ float red[256];
  catv[t] = catc[b*256 + t];
  __syncthreads();
  float evl[4];
#pragma unroll
  for (int r2=0;r2<4;r2++){
    int l = t + r2*256;
    const u16x8* row = (const u16x8*)(y1 + ((long)l*64 + b)*256);
    float acc = 0.f;
    for (int f8=0; f8<32; f8++){
      u16x8 v = row[f8];
#pragma unroll
      for (int k=0;k<8;k++) acc += b2f(v[k]) * catv[f8*8+k];
    }
    ev[l] = acc; evl[r2] = acc;
  }
  float mx = fmaxf(fmaxf(evl[0],evl[1]), fmaxf(evl[2],evl[3]));
  red[t] = mx;
  __syncthreads();
  for (int s=128; s>0; s>>=1){ if (t < s) red[t] = fmaxf(red[t], red[t+s]); __syncthreads(); }
  float m = red[0];
  __syncthreads();
  float sum = 0.f;
#pragma unroll
  for (int r2=0;r2<4;r2++){
    int l = t + r2*256;
    float e = __expf(ev[l] - m);
    ev[l] = e; sum += e;
  }
  red[t] = sum;
  __syncthreads();
  for (int s=128; s>0; s>>=1){ if (t < s) red[t] += red[t+s]; __syncthreads(); }
  float rz = __builtin_amdgcn_rcpf(red[0]);
#pragma unroll
  for (int r2=0;r2<4;r2++){
    int l = t + r2*256;
    sT[(long)l*64 + b] = ev[l] * rz;
  }
#pragma unroll
  for (int r2=0;r2<4;r2++){
    int j = t + r2*256;
    const float* wr = (j < 512) ? (Wih2f + (long)j*512 + 256)
                                : (Wih2b + (long)(j-512)*512 + 256);
    const float4* w4 = (const float4*)wr;
    float acc = 0.f;
#pragma unroll 8
    for (int f4=0; f4<64; f4++){
      float4 v = w4[f4];
      acc += v.x*catv[f4*4+0] + v.y*catv[f4*4+1] + v.z*catv[f4*4+2] + v.w*catv[f4*4+3];
    }
    proj[b*1024 + j] = acc;
  }
}

// ---------------- feats = out2 @ Wout.T + bout ----------------
__global__ __launch_bounds__(256) void featk(const u16* __restrict__ y2,
    const float* __restrict__ Wout, const float* __restrict__ bout, float* __restrict__ feats)
{
  __shared__ float wlds[1280];
  int t = threadIdx.x;
  for (int k=t;k<1280;k+=256) wlds[k] = Wout[k];
  __syncthreads();
  long i = (long)blockIdx.x*256 + t;
  const u16x8* row = (const u16x8*)(y2 + i*256);
  float acc[5] = {0.f,0.f,0.f,0.f,0.f};
  for (int f8=0; f8<32; f8++){
    u16x8 v = row[f8];
#pragma unroll
    for (int k=0;k<8;k++){
      float x = b2f(v[k]);
      int f = f8*8 + k;
#pragma unroll
      for (int c=0;c<5;c++) acc[c] += x * wlds[c*256 + f];
    }
  }
#pragma unroll
  for (int c=0;c<5;c++) feats[i*5 + c] = acc[c] + bout[c];
}

// ---------------- CRF forward, exp domain: sc[c] = M + ln E[c] ----------------
__global__ void crf_kernel(const float* __restrict__ feats, const float* __restrict__ masks,
                           const float* __restrict__ trans, float* __restrict__ out)
{
  int b = threadIdx.x;  // 64
  float etr[5][5], tr4[5];
#pragma unroll
  for (int c=0;c<5;c++)
#pragma unroll
    for (int cp=0;cp<5;cp++) etr[c][cp] = __expf(trans[c*5+cp]);  // e^-10000 -> 0
#pragma unroll
  for (int cp=0;cp<5;cp++) tr4[cp] = trans[4*5+cp];   // STOP row
  float E[5] = {0.f, 0.f, 0.f, 1.f, 0.f};             // exp(sc), START=3
  float M = 0.f;
  const float* fpB = feats + (long)b*5120;
  float ftn[5], mtn;
#pragma unroll
  for (int c=0;c<5;c++) ftn[c] = fpB[c];
  mtn = masks[b*1024];
  for (int l=0;l<1024;l++){
    float ft[5]; float mt = mtn;
#pragma unroll
    for (int c=0;c<5;c++) ft[c] = ftn[c];
    if (l < 1023){
      const float* fp = fpB + (l + 1)*5;
#pragma unroll
      for (int c=0;c<5;c++) ftn[c] = fp[c];
      mtn = masks[b*1024 + l + 1];
    }
    float En[5];
#pragma unroll
    for (int c=0;c<5;c++){
      float S = E[0]*etr[c][0];
#pragma unroll
      for (int cp=1;cp<5;cp++) S = fmaf(E[cp], etr[c][cp], S);
      En[c] = S * __expf(ft[c]);
    }
    bool take = (mt > 0.5f);
#pragma unroll
    for (int c=0;c<5;c++) E[c] = take ? En[c] : E[c];
    // exact power-of-2 renorm
    float mx = fmaxf(fmaxf(fmaxf(E[0],E[1]), fmaxf(E[2],E[3])), E[4]);
    int k = (int)((__builtin_bit_cast(unsigned, mx) >> 23) & 0xFFu) - 127;
    float s = __builtin_bit_cast(float, (unsigned)(127 - k) << 23);
#pragma unroll
    for (int c=0;c<5;c++) E[c] *= s;
    M = fmaf((float)k, 0.6931471805599453f, M);
  }
  float Sf = 0.f;
#pragma unroll
  for (int cp=0;cp<5;cp++) Sf = fmaf(E[cp], __expf(tr4[cp]), Sf);
  out[b] = M + __logf(Sf);
}

// ---------------- launcher ----------------
extern "C" void kernel_launch(void* const* d_in, const int* in_sizes, int n_in,
                              void* d_out, int out_size, void* d_ws, size_t ws_size,
                              hipStream_t stream)
{
  const int*   sent  = (const int*)  d_in[0];
  const float* masks = (const float*)d_in[1];
  const float* emb   = (const float*)d_in[2];
  const float* Wih1f = (const float*)d_in[3];
  const float* Whh1f = (const float*)d_in[4];
  const float* bih1f = (const float*)d_in[5];
  const float* bhh1f = (const float*)d_in[6];
  const float* Wih1b = (const float*)d_in[7];
  const float* Whh1b = (const float*)d_in[8];
  const float* bih1b = (const float*)d_in[9];
  const float* bhh1b = (const float*)d_in[10];
  const float* Wih2f = (const float*)d_in[11];
  const float* Whh2f = (const float*)d_in[12];
  const float* bih2f = (const float*)d_in[13];
  const float* bhh2f = (const float*)d_in[14];
  const float* Wih2b = (const float*)d_in[15];
  const float* Whh2b = (const float*)d_in[16];
  const float* bih2b = (const float*)d_in[17];
  const float* bhh2b = (const float*)d_in[18];
  const float* Wout  = (const float*)d_in[19];
  const float* bout  = (const float*)d_in[20];
  const float* trans = (const float*)d_in[21];
  const float* h0    = (const float*)d_in[22];
  const float* c0    = (const float*)d_in[23];
  const float* h02   = (const float*)d_in[24];
  const float* c02   = (const float*)d_in[25];
  float* out = (float*)d_out;

  // workspace layout (aliased: X/y1/y2 share, G per layer shares). ~170.7 MB.
  char* ws = (char*)d_ws;
  u16*   Ybuf  = (u16*)(ws + 0);              // 33,554,432 B: X, then y1, then y2
  u16*   Gbuf  = (u16*)(ws + 33554432);       // 134,217,728 B: G'' per layer
  u16*   W1cat = (u16*)(ws + 167772160);      // 524,288 B (permuted cols)
  u16*   WAcat = (u16*)(ws + 168296448);      // 524,288 B (permuted cols)
  float* b1cat = (float*)(ws + 168820736);    // 4,096 B (permuted)
  float* b2cat = (float*)(ws + 168824832);    // 4,096 B (permuted)
  float* catcb = (float*)(ws + 168828928);    // 65,536 B
  float* sbuf  = (float*)(ws + 168894464);    // 262,144 B  (sT[l][64])
  float* projb = (float*)(ws + 169156608);    // 262,144 B (original col order)
  float* featb = (float*)(ws + 169418752);    // 1,310,720 B

  conv_weights<<<1024, 256, 0, stream>>>(Wih1f, Wih1b, bih1f, bhh1f, bih1b, bhh1b,
                                         Wih2f, Wih2b, bih2f, bhh2f, bih2b, bhh2b,
                                         W1cat, WAcat, b1cat, b2cat);
  embed_gather<<<16384, 256, 0, stream>>>(sent, emb, Ybuf);
  gemm_bt<<<dim3(512, 8), 256, 0, stream>>>(Ybuf, W1cat, b1cat, Gbuf, 65536, 1024, 256);
  lstm_layer<<<16, 1024, 0, stream>>>(Gbuf, Whh1f, Whh1b, h0, c0, nullptr, nullptr, Ybuf, catcb);
  attn_kernel<<<64, 256, 0, stream>>>(Ybuf, catcb, Wih2f, Wih2b, sbuf, projb);
  gemm_bt<<<dim3(512, 8), 256, 0, stream>>>(Ybuf, WAcat, b2cat, Gbuf, 65536, 1024, 256);
  lstm_layer<<<16, 1024, 0, stream>>>(Gbuf, Whh2f, Whh2b, h02, c02, sbuf, projb, Ybuf, nullptr);
  featk<<<256, 256, 0, stream>>>(Ybuf, Wout, bout, featb);
  crf_kernel<<<1, 64, 0, stream>>>(featb, masks, trans, out);
}

// Round 11
// 2117.566 us; speedup vs baseline: 1.1104x; 1.1104x over previous
//
#include <hip/hip_runtime.h>
#include <hip/hip_bf16.h>

// BiLSTM-CRF forward. B=64, L=1024, E=256, H=128 (per dir), C=5, V=32000.
// R10: weight-column permutation fixed to jp = dir*512 + u*4 + g (g FASTEST).
// G page layout is u*64 + b*8 + g*2 bytes, so g-fastest makes each gemm store
// instruction fill 8B chunks densely (4 g per chunk, r2 fills adjacent b) ->
// G write amplification 4x -> 1x. LSTM identical to R8/R9 skeleton.

typedef unsigned short u16;
typedef unsigned int u32;
typedef __bf16 v8bf __attribute__((ext_vector_type(8)));
typedef float  v4f  __attribute__((ext_vector_type(4)));
typedef unsigned short u16x8 __attribute__((ext_vector_type(8)));
typedef unsigned short u16x4 __attribute__((ext_vector_type(4)));

__device__ __forceinline__ float b2f(u16 b){
  return __builtin_bit_cast(float, ((unsigned)b) << 16);
}
__device__ __forceinline__ u16 f2b(float x){           // RNE f32->bf16
  unsigned u = __builtin_bit_cast(unsigned, x);
  unsigned r = (u + 0x7FFFu + ((u >> 16) & 1u)) >> 16;
  return (u16)r;
}
__device__ __forceinline__ float xor8(float x){        // lane <- lane^8 (row_ror:8)
  int t = __builtin_amdgcn_mov_dpp(__builtin_bit_cast(int, x), 0x128, 0xF, 0xF, true);
  return __builtin_bit_cast(float, t);
}
// LDS-only workgroup barrier (kept from R9; neutral but harmless)
__device__ __forceinline__ void lds_only_barrier(){
  __builtin_amdgcn_fence(__ATOMIC_RELEASE, "workgroup", "local");
  __builtin_amdgcn_s_barrier();
  __builtin_amdgcn_fence(__ATOMIC_ACQUIRE, "workgroup", "local");
}

// ---------------- weight prep: permuted concat + fp32->bf16 ----------------
// permuted col jp: dirj=jp>>9, u=(jp>>2)&127, g=jp&3; original row r = g*128+u
__global__ __launch_bounds__(256) void conv_weights(
    const float* __restrict__ Wih1f, const float* __restrict__ Wih1b,
    const float* __restrict__ bih1f, const float* __restrict__ bhh1f,
    const float* __restrict__ bih1b, const float* __restrict__ bhh1b,
    const float* __restrict__ Wih2f, const float* __restrict__ Wih2b,
    const float* __restrict__ bih2f, const float* __restrict__ bhh2f,
    const float* __restrict__ bih2b, const float* __restrict__ bhh2b,
    u16* __restrict__ W1cat, u16* __restrict__ WAcat,
    float* __restrict__ b1cat, float* __restrict__ b2cat)
{
  int gid = blockIdx.x * 256 + threadIdx.x;   // 1024*256 = 262144
  int j = gid >> 8, e = gid & 255;            // j = permuted column jp
  int dirj = j >> 9, u = (j >> 2) & 127, g = j & 3;
  int r = g*128 + u;                          // 0..511
  float w1 = dirj ? Wih1b[r*256 + e] : Wih1f[r*256 + e];
  float wa = dirj ? Wih2b[(long)r*512 + e] : Wih2f[(long)r*512 + e];  // cols 0..255
  W1cat[gid] = f2b(w1);
  WAcat[gid] = f2b(wa);
  if (e == 0){
    b1cat[j] = dirj ? (bih1b[r] + bhh1b[r]) : (bih1f[r] + bhh1f[r]);
    b2cat[j] = dirj ? (bih2b[r] + bhh2b[r]) : (bih2f[r] + bhh2f[r]);
  }
}

// ---------------- embedding gather (flat order == reshape(L,B,E)) ----------------
__global__ __launch_bounds__(256) void embed_gather(
    const int* __restrict__ sent, const float* __restrict__ emb, u16* __restrict__ X)
{
  int w = threadIdx.x >> 6, lane = threadIdx.x & 63;
  long i = (long)blockIdx.x * 4 + w;          // row of X, 0..65535
  int idx = sent[i];
  const float4* src = (const float4*)(emb + (long)idx * 256);
  float4 v = src[lane];
  u16x4 o; o[0] = f2b(v.x); o[1] = f2b(v.y); o[2] = f2b(v.z); o[3] = f2b(v.w);
  *(u16x4*)(X + i*256 + lane*4) = o;
}

// ---- bf16 MFMA GEMM, A[MxK] rm, Bperm[NxK] rm, +bias; writes G''[grp][l][thr][4] ----
// permuted col j: dirj=j>>9, u=(j>>2)&127, g=j&3
// grp=dirj*8+(b>>3); thr=u*8+(b&7); z=g  (page layout u*64 + b*8 + g*2 bytes, dense)
__global__ __launch_bounds__(256) void gemm_bt(
    const u16* __restrict__ A, const u16* __restrict__ Bm,
    const float* __restrict__ bias, u16* __restrict__ Gp,
    int M, int N, int K)
{
  __shared__ __align__(16) u16 As[128*64];
  __shared__ __align__(16) u16 Bs[128*64];
  int tid = threadIdx.x;
  int w = tid >> 6, lane = tid & 63;
  int lq = lane & 15, quad = lane >> 4;
  int wm = w & 1, wn = w >> 1;
  long m0 = (long)blockIdx.x * 128;
  int n0 = blockIdx.y * 128;
  v4f acc[4][4];
  v4f zero = {0.f, 0.f, 0.f, 0.f};
#pragma unroll
  for (int i=0;i<4;i++)
#pragma unroll
    for (int j=0;j<4;j++) acc[i][j] = zero;

  for (int k0 = 0; k0 < K; k0 += 64){
#pragma unroll
    for (int c = 0; c < 4; c++){
      int lin = c*256 + tid;
      int row = lin >> 3, chunk = lin & 7;            // 128 rows x 8 chunks(16B)
      u16x8 av = *(const u16x8*)(A + (m0+row)*K + k0 + chunk*8);
      u16x8 bv = *(const u16x8*)(Bm + ((long)(n0+row))*K + k0 + chunk*8);
      int sw = chunk ^ (row & 7);                     // XOR swizzle vs bank conflicts
      *(u16x8*)(As + row*64 + sw*8) = av;
      *(u16x8*)(Bs + row*64 + sw*8) = bv;
    }
    __syncthreads();
#pragma unroll
    for (int s = 0; s < 2; s++){
      v8bf af[4], bf_[4];
#pragma unroll
      for (int i=0;i<4;i++){
        int row = wm*64 + i*16 + lq;
        int ch  = (s*4 + quad) ^ (row & 7);
        af[i] = __builtin_bit_cast(v8bf, *(const u16x8*)(As + row*64 + ch*8));
      }
#pragma unroll
      for (int j=0;j<4;j++){
        int row = wn*64 + j*16 + lq;
        int ch  = (s*4 + quad) ^ (row & 7);
        bf_[j] = __builtin_bit_cast(v8bf, *(const u16x8*)(Bs + row*64 + ch*8));
      }
#pragma unroll
      for (int i=0;i<4;i++)
#pragma unroll
        for (int j=0;j<4;j++)
          acc[i][j] = __builtin_amdgcn_mfma_f32_16x16x32_bf16(af[i], bf_[j], acc[i][j], 0, 0, 0);
    }
    __syncthreads();
  }
#pragma unroll
  for (int jt=0;jt<4;jt++){
    int j = n0 + wn*64 + jt*16 + lq;          // permuted column
    float bv = bias[j];
    int dirj = j >> 9, u = (j >> 2) & 127, g = j & 3;
    int tidl = u*8;
#pragma unroll
    for (int i16=0;i16<4;i16++){
#pragma unroll
      for (int r2=0;r2<4;r2++){
        long i = m0 + wm*64 + i16*16 + quad*4 + r2;
        int bb = (int)(i & 63); long l = i >> 6;
        long off = ((long)(dirj*8 + (bb>>3)) << 22) + (l << 12)
                 + (long)(tidl + (bb&7))*4 + g;
        Gp[off] = f2b(acc[i16][jt][r2] + bv);
      }
    }
  }
}

// ---------------- persistent BiLSTM layer: 16 WGs x 1024 thr (2 dirs x 8 bgroups) ----
// Thread (v=tid>>6, quad, lq): owns ONE cell: batch=b0+(lq&7), unit U=v*8+2q+(lq>>3).
// MFMA: A rows = gate(m&3) of unit v*8+tau+2*(m>>2); B cols 0..7 = batches (8-15 pad,
// never consumed -> lanes lq>=8 skip LDS reads, keep zero frags). tau=1 cells pulled
// to lanes lq>=8 via DPP row_ror:8. G'': [grp][l][tid][4], per-step dwordx2, dbuf.
__global__ __launch_bounds__(1024, 4) void lstm_layer(
    const u16* __restrict__ G, const float* __restrict__ WhhF, const float* __restrict__ WhhB,
    const float* __restrict__ h0, const float* __restrict__ c0,
    const float* __restrict__ sT, const float* __restrict__ proj,
    u16* __restrict__ Y, float* __restrict__ catOut)
{
  int blk = blockIdx.x;
  int dir = blk >> 3, bg = blk & 7, b0 = bg * 8;
  int tid = threadIdx.x, v = tid >> 6, lane = tid & 63;
  int quad = lane >> 4, lq = lane & 15;
  int b7 = lq & 7, tb = lq >> 3;
  int U = v*8 + 2*quad + tb;                  // this thread's hidden unit
  int batch = b0 + b7;
  const float* Whh = dir ? WhhB : WhhF;

  __shared__ __align__(16) u16 hbuf[2][1024]; // h[8 batches][128 units], XOR-swizzled

  // A-frags in registers: lane holds A[m=lq][k=ks*32+quad*8+j]
  // tile tau row m: gate = m&3, unit = v*8 + tau + 2*(m>>2)
  v8bf Af[2][4];
  {
    int gate = lq & 3;
#pragma unroll
    for (int tau=0;tau<2;tau++){
      int unit = v*8 + tau + 2*(lq>>2);
      const float* wr = Whh + (long)(gate*128 + unit)*128;
#pragma unroll
      for (int ks=0;ks<4;ks++){
        u16x8 tmp;
#pragma unroll
        for (int jj=0;jj<8;jj++) tmp[jj] = f2b(wr[ks*32 + quad*8 + jj]);
        Af[tau][ks] = __builtin_bit_cast(v8bf, tmp);
      }
    }
  }

  int wOff = b7*128 + ((v ^ b7) * 8) + 2*quad + tb;
  int rOff[4];
#pragma unroll
  for (int ks=0;ks<4;ks++) rOff[ks] = lq*128 + (((ks*4 + quad) ^ lq) * 8);

  float cc = c0[dir*8192 + batch*128 + U];
  u16 h0b = f2b(h0[dir*8192 + batch*128 + U]);
  hbuf[0][wOff] = h0b;

  // attention fold (LSTM2): pr[g] = 64*proj[batch, dir*512 + g*128 + U]
  bool att = (proj != nullptr);
  float pr[4];
  if (att){
#pragma unroll
    for (int g=0;g<4;g++)
      pr[g] = 64.0f * proj[(long)batch*1024 + dir*512 + g*128 + U];
  }

  const u16x4* Gp = (const u16x4*)(G + ((size_t)blk << 22)) + tid;
  long dl = dir ? -1 : 1;
  long l0 = dir ? 1023 : 0;
  u16x4 gbuf[2];
  gbuf[0] = Gp[l0 << 10];
  gbuf[1] = Gp[(l0 + dl) << 10];
  const u16x4* gpf = Gp + ((l0 + 2*dl) << 10);  // runs 2 past end: ws-internal, harmless
  u16* yp = Y + (l0*64 + batch)*256 + dir*128 + U;

  // softmax scalar, depth-2 prefetched like gbuf (LSTM2 only)
  float sv[2] = {0.f, 0.f};
  const float* spf = nullptr;
  if (att){
    const float* sp0 = sT + l0*64 + batch;
    sv[0] = sp0[0];
    sv[1] = sp0[dl*64];
    spf = sp0 + 2*dl*64;                      // runs 2 past end: ws-internal, harmless
  }

  // deferred Y store: step t's h stored at top of step t+1.
  u16 hbPrev = h0b;
  u16* ypPrev = yp;

  u16x8 zz = {0,0,0,0,0,0,0,0};
  v8bf bh[4];
#pragma unroll
  for (int ks=0;ks<4;ks++) bh[ks] = __builtin_bit_cast(v8bf, zz);

  bool low = (tb == 0);
  const float NL2E = -1.4426950408889634f;
  const float N2L2E = -2.8853900817779268f;
  v4f zero4 = {0.f, 0.f, 0.f, 0.f};
  __syncthreads();   // full barrier once before the loop (h0 writes + init)

#pragma unroll 2
  for (int it = 0; it < 1024; ++it){
    int slot = it & 1;
    // deferred Y store of previous step's h (first iter: h0 -> overwritten later)
    *ypPrev = hbPrev;
    // gates for this step
    float gc[4];
#pragma unroll
    for (int g=0; g<4; g++) gc[g] = b2f(gbuf[slot][g]);
    gbuf[slot] = *gpf;                        // prefetch it+2 (same parity slot)
    gpf += dl << 10;
    float s = 0.f;
    if (att){
      s = sv[slot];
      sv[slot] = *spf;
      spf += dl*64;
    }
    // h fragments (real cols only)
    if (lq < 8){
#pragma unroll
      for (int ks=0;ks<4;ks++)
        bh[ks] = __builtin_bit_cast(v8bf, *(const u16x8*)(&hbuf[slot][rOff[ks]]));
    }
    // 2x2 MFMA tree per tau (chain depth 2)
    v4f aA0 = __builtin_amdgcn_mfma_f32_16x16x32_bf16(Af[0][0], bh[0], zero4, 0,0,0);
    v4f aB0 = __builtin_amdgcn_mfma_f32_16x16x32_bf16(Af[0][2], bh[2], zero4, 0,0,0);
    v4f aA1 = __builtin_amdgcn_mfma_f32_16x16x32_bf16(Af[1][0], bh[0], zero4, 0,0,0);
    v4f aB1 = __builtin_amdgcn_mfma_f32_16x16x32_bf16(Af[1][2], bh[2], zero4, 0,0,0);
    aA0 = __builtin_amdgcn_mfma_f32_16x16x32_bf16(Af[0][1], bh[1], aA0, 0,0,0);
    aB0 = __builtin_amdgcn_mfma_f32_16x16x32_bf16(Af[0][3], bh[3], aB0, 0,0,0);
    aA1 = __builtin_amdgcn_mfma_f32_16x16x32_bf16(Af[1][1], bh[1], aA1, 0,0,0);
    aB1 = __builtin_amdgcn_mfma_f32_16x16x32_bf16(Af[1][3], bh[3], aB1, 0,0,0);

    float val[4];
#pragma unroll
    for (int r=0;r<4;r++){
      float a0 = aA0[r] + aB0[r];
      float a1 = xor8(aA1[r] + aB1[r]);
      val[r] = (low ? a0 : a1) + gc[r];
    }
    if (att){
#pragma unroll
      for (int r=0;r<4;r++) val[r] = fmaf(s, pr[r], val[r]);
    }

    float i_ = val[0], f_ = val[1], g_ = val[2], o_ = val[3];
    float ef = __builtin_amdgcn_exp2f(f_ * NL2E);
    float ei = __builtin_amdgcn_exp2f(i_ * NL2E);
    float eg = __builtin_amdgcn_exp2f(fminf(g_ * N2L2E, 115.0f));
    float sf = __builtin_amdgcn_rcpf(1.0f + ef);
    float pp = (1.0f - eg) * __builtin_amdgcn_rcpf((1.0f + ei) * (1.0f + eg));
    float c2 = fmaf(cc, sf, pp);
    cc = c2;
    float eo = __builtin_amdgcn_exp2f(o_ * NL2E);
    float ec = __builtin_amdgcn_exp2f(fminf(c2 * N2L2E, 115.0f));
    float hv = (1.0f - ec) * __builtin_amdgcn_rcpf((1.0f + eo) * (1.0f + ec));

    u16 hb = f2b(hv);
    hbuf[slot^1][wOff] = hb;
    hbPrev = hb;
    ypPrev = yp;
    yp += dl*16384;
    lds_only_barrier();   // LDS ordering only
  }
  *ypPrev = hbPrev;                           // last step's h
  if (catOut)
    catOut[(long)batch*256 + dir*128 + U] = cc;
}

// ---------------- attention: e = fbout . catc, softmax over L, proj = catc @ Wih2[:,256:].T ----
// s written TRANSPOSED: sT[l*64 + b]. proj in ORIGINAL column order.
__global__ __launch_bounds__(256) void attn_kernel(
    const u16* __restrict__ y1, const float* __restrict__ catc,
    const float* __restrict__ Wih2f, const float* __restrict__ Wih2b,
    float* __restrict__ sT, float* __restrict__ proj)
{
  int b = blockIdx.x, t = threadIdx.x;
  __shared__ float catv[256];
  __shared__ float ev[1024];
  __shared__ float red[256];
  catv[t] = catc[b*256 + t];
  __syncthreads();
  float evl[4];
#pragma unroll
  for (int r2=0;r2<4;r2++){
    int l = t + r2*256;
    const u16x8* row = (const u16x8*)(y1 + ((long)l*64 + b)*256);
    float acc = 0.f;
    for (int f8=0; f8<32; f8++){
      u16x8 v = row[f8];
#pragma unroll
      for (int k=0;k<8;k++) acc += b2f(v[k]) * catv[f8*8+k];
    }
    ev[l] = acc; evl[r2] = acc;
  }
  float mx = fmaxf(fmaxf(evl[0],evl[1]), fmaxf(evl[2],evl[3]));
  red[t] = mx;
  __syncthreads();
  for (int s=128; s>0; s>>=1){ if (t < s) red[t] = fmaxf(red[t], red[t+s]); __syncthreads(); }
  float m = red[0];
  __syncthreads();
  float sum = 0.f;
#pragma unroll
  for (int r2=0;r2<4;r2++){
    int l = t + r2*256;
    float e = __expf(ev[l] - m);
    ev[l] = e; sum += e;
  }
  red[t] = sum;
  __syncthreads();
  for (int s=128; s>0; s>>=1){ if (t < s) red[t] += red[t+s]; __syncthreads(); }
  float rz = __builtin_amdgcn_rcpf(red[0]);
#pragma unroll
  for (int r2=0;r2<4;r2++){
    int l = t + r2*256;
    sT[(long)l*64 + b] = ev[l] * rz;
  }
#pragma unroll
  for (int r2=0;r2<4;r2++){
    int j = t + r2*256;
    const float* wr = (j < 512) ? (Wih2f + (long)j*512 + 256)
                                : (Wih2b + (long)(j-512)*512 + 256);
    const float4* w4 = (const float4*)wr;
    float acc = 0.f;
#pragma unroll 8
    for (int f4=0; f4<64; f4++){
      float4 v = w4[f4];
      acc += v.x*catv[f4*4+0] + v.y*catv[f4*4+1] + v.z*catv[f4*4+2] + v.w*catv[f4*4+3];
    }
    proj[b*1024 + j] = acc;
  }
}

// ---------------- feats = out2 @ Wout.T + bout ----------------
__global__ __launch_bounds__(256) void featk(const u16* __restrict__ y2,
    const float* __restrict__ Wout, const float* __restrict__ bout, float* __restrict__ feats)
{
  __shared__ float wlds[1280];
  int t = threadIdx.x;
  for (int k=t;k<1280;k+=256) wlds[k] = Wout[k];
  __syncthreads();
  long i = (long)blockIdx.x*256 + t;
  const u16x8* row = (const u16x8*)(y2 + i*256);
  float acc[5] = {0.f,0.f,0.f,0.f,0.f};
  for (int f8=0; f8<32; f8++){
    u16x8 v = row[f8];
#pragma unroll
    for (int k=0;k<8;k++){
      float x = b2f(v[k]);
      int f = f8*8 + k;
#pragma unroll
      for (int c=0;c<5;c++) acc[c] += x * wlds[c*256 + f];
    }
  }
#pragma unroll
  for (int c=0;c<5;c++) feats[i*5 + c] = acc[c] + bout[c];
}

// ---------------- CRF forward, exp domain: sc[c] = M + ln E[c] ----------------
__global__ void crf_kernel(const float* __restrict__ feats, const float* __restrict__ masks,
                           const float* __restrict__ trans, float* __restrict__ out)
{
  int b = threadIdx.x;  // 64
  float etr[5][5], tr4[5];
#pragma unroll
  for (int c=0;c<5;c++)
#pragma unroll
    for (int cp=0;cp<5;cp++) etr[c][cp] = __expf(trans[c*5+cp]);  // e^-10000 -> 0
#pragma unroll
  for (int cp=0;cp<5;cp++) tr4[cp] = trans[4*5+cp];   // STOP row
  float E[5] = {0.f, 0.f, 0.f, 1.f, 0.f};             // exp(sc), START=3
  float M = 0.f;
  const float* fpB = feats + (long)b*5120;
  float ftn[5], mtn;
#pragma unroll
  for (int c=0;c<5;c++) ftn[c] = fpB[c];
  mtn = masks[b*1024];
  for (int l=0;l<1024;l++){
    float ft[5]; float mt = mtn;
#pragma unroll
    for (int c=0;c<5;c++) ft[c] = ftn[c];
    if (l < 1023){
      const float* fp = fpB + (l + 1)*5;
#pragma unroll
      for (int c=0;c<5;c++) ftn[c] = fp[c];
      mtn = masks[b*1024 + l + 1];
    }
    float En[5];
#pragma unroll
    for (int c=0;c<5;c++){
      float S = E[0]*etr[c][0];
#pragma unroll
      for (int cp=1;cp<5;cp++) S = fmaf(E[cp], etr[c][cp], S);
      En[c] = S * __expf(ft[c]);
    }
    bool take = (mt > 0.5f);
#pragma unroll
    for (int c=0;c<5;c++) E[c] = take ? En[c] : E[c];
    // exact power-of-2 renorm
    float mx = fmaxf(fmaxf(fmaxf(E[0],E[1]), fmaxf(E[2],E[3])), E[4]);
    int k = (int)((__builtin_bit_cast(unsigned, mx) >> 23) & 0xFFu) - 127;
    float s = __builtin_bit_cast(float, (unsigned)(127 - k) << 23);
#pragma unroll
    for (int c=0;c<5;c++) E[c] *= s;
    M = fmaf((float)k, 0.6931471805599453f, M);
  }
  float Sf = 0.f;
#pragma unroll
  for (int cp=0;cp<5;cp++) Sf = fmaf(E[cp], __expf(tr4[cp]), Sf);
  out[b] = M + __logf(Sf);
}

// ---------------- launcher ----------------
extern "C" void kernel_launch(void* const* d_in, const int* in_sizes, int n_in,
                              void* d_out, int out_size, void* d_ws, size_t ws_size,
                              hipStream_t stream)
{
  const int*   sent  = (const int*)  d_in[0];
  const float* masks = (const float*)d_in[1];
  const float* emb   = (const float*)d_in[2];
  const float* Wih1f = (const float*)d_in[3];
  const float* Whh1f = (const float*)d_in[4];
  const float* bih1f = (const float*)d_in[5];
  const float* bhh1f = (const float*)d_in[6];
  const float* Wih1b = (const float*)d_in[7];
  const float* Whh1b = (const float*)d_in[8];
  const float* bih1b = (const float*)d_in[9];
  const float* bhh1b = (const float*)d_in[10];
  const float* Wih2f = (const float*)d_in[11];
  const float* Whh2f = (const float*)d_in[12];
  const float* bih2f = (const float*)d_in[13];
  const float* bhh2f = (const float*)d_in[14];
  const float* Wih2b = (const float*)d_in[15];
  const float* Whh2b = (const float*)d_in[16];
  const float* bih2b = (const float*)d_in[17];
  const float* bhh2b = (const float*)d_in[18];
  const float* Wout  = (const float*)d_in[19];
  const float* bout  = (const float*)d_in[20];
  const float* trans = (const float*)d_in[21];
  const float* h0    = (const float*)d_in[22];
  const float* c0    = (const float*)d_in[23];
  const float* h02   = (const float*)d_in[24];
  const float* c02   = (const float*)d_in[25];
  float* out = (float*)d_out;

  // workspace layout (aliased: X/y1/y2 share, G per layer shares). ~170.7 MB.
  char* ws = (char*)d_ws;
  u16*   Ybuf  = (u16*)(ws + 0);              // 33,554,432 B: X, then y1, then y2
  u16*   Gbuf  = (u16*)(ws + 33554432);       // 134,217,728 B: G'' per layer
  u16*   W1cat = (u16*)(ws + 167772160);      // 524,288 B (permuted cols, g fastest)
  u16*   WAcat = (u16*)(ws + 168296448);      // 524,288 B (permuted cols, g fastest)
  float* b1cat = (float*)(ws + 168820736);    // 4,096 B (permuted)
  float* b2cat = (float*)(ws + 168824832);    // 4,096 B (permuted)
  float* catcb = (float*)(ws + 168828928);    // 65,536 B
  float* sbuf  = (float*)(ws + 168894464);    // 262,144 B  (sT[l][64])
  float* projb = (float*)(ws + 169156608);    // 262,144 B (original col order)
  float* featb = (float*)(ws + 169418752);    // 1,310,720 B

  conv_weights<<<1024, 256, 0, stream>>>(Wih1f, Wih1b, bih1f, bhh1f, bih1b, bhh1b,
                                         Wih2f, Wih2b, bih2f, bhh2f, bih2b, bhh2b,
                                         W1cat, WAcat, b1cat, b2cat);
  embed_gather<<<16384, 256, 0, stream>>>(sent, emb, Ybuf);
  gemm_bt<<<dim3(512, 8), 256, 0, stream>>>(Ybuf, W1cat, b1cat, Gbuf, 65536, 1024, 256);
  lstm_layer<<<16, 1024, 0, stream>>>(Gbuf, Whh1f, Whh1b, h0, c0, nullptr, nullptr, Ybuf, catcb);
  attn_kernel<<<64, 256, 0, stream>>>(Ybuf, catcb, Wih2f, Wih2b, sbuf, projb);
  gemm_bt<<<dim3(512, 8), 256, 0, stream>>>(Ybuf, WAcat, b2cat, Gbuf, 65536, 1024, 256);
  lstm_layer<<<16, 1024, 0, stream>>>(Gbuf, Whh2f, Whh2b, h02, c02, sbuf, projb, Ybuf, nullptr);
  featk<<<256, 256, 0, stream>>>(Ybuf, Wout, bout, featb);
  crf_kernel<<<1, 64, 0, stream>>>(featb, masks, trans, out);
}

// Round 12
// 1740.267 us; speedup vs baseline: 1.3511x; 1.2168x over previous
//
#include <hip/hip_runtime.h>
#include <hip/hip_bf16.h>

// BiLSTM-CRF forward. B=64, L=1024, E=256, H=128 (per dir), C=5, V=32000.
// R11: 32 persistent LSTM WGs (2 dirs x 16 batch-groups of 4), 512 thr/WG.
// Wave v computes 4 gate-interleaved A tiles (units v*16+4q+tau); MFMA B cols
// 0..3 real, 4..15 pad (zero reg frags, lanes lq>=4 skip LDS). Cells
// redistributed so every lane owns exactly 1 cell: lane b3+4*tau' takes
// acc[tau'] from lane b3 via v_mov_dpp row_ror:{12,8,4}. Per-CU VALU halves.
// G layout [grp32][l][thr512][4] (g fastest in gemm cols, R10 density kept).

typedef unsigned short u16;
typedef unsigned int u32;
typedef __bf16 v8bf __attribute__((ext_vector_type(8)));
typedef float  v4f  __attribute__((ext_vector_type(4)));
typedef unsigned short u16x8 __attribute__((ext_vector_type(8)));
typedef unsigned short u16x4 __attribute__((ext_vector_type(4)));

__device__ __forceinline__ float b2f(u16 b){
  return __builtin_bit_cast(float, ((unsigned)b) << 16);
}
__device__ __forceinline__ u16 f2b(float x){           // RNE f32->bf16
  unsigned u = __builtin_bit_cast(unsigned, x);
  unsigned r = (u + 0x7FFFu + ((u >> 16) & 1u)) >> 16;
  return (u16)r;
}
// dst[i] = src[(i+N)&15] within each row of 16 lanes
__device__ __forceinline__ float ror4(float x){
  return __builtin_bit_cast(float, __builtin_amdgcn_mov_dpp(
      __builtin_bit_cast(int, x), 0x124, 0xF, 0xF, true));
}
__device__ __forceinline__ float ror8(float x){
  return __builtin_bit_cast(float, __builtin_amdgcn_mov_dpp(
      __builtin_bit_cast(int, x), 0x128, 0xF, 0xF, true));
}
__device__ __forceinline__ float ror12(float x){
  return __builtin_bit_cast(float, __builtin_amdgcn_mov_dpp(
      __builtin_bit_cast(int, x), 0x12C, 0xF, 0xF, true));
}
// LDS-only workgroup barrier
__device__ __forceinline__ void lds_only_barrier(){
  __builtin_amdgcn_fence(__ATOMIC_RELEASE, "workgroup", "local");
  __builtin_amdgcn_s_barrier();
  __builtin_amdgcn_fence(__ATOMIC_ACQUIRE, "workgroup", "local");
}

// ---------------- weight prep: permuted concat + fp32->bf16 ----------------
// permuted col jp: dirj=jp>>9, u=(jp>>2)&127, g=jp&3; original row r = g*128+u
__global__ __launch_bounds__(256) void conv_weights(
    const float* __restrict__ Wih1f, const float* __restrict__ Wih1b,
    const float* __restrict__ bih1f, const float* __restrict__ bhh1f,
    const float* __restrict__ bih1b, const float* __restrict__ bhh1b,
    const float* __restrict__ Wih2f, const float* __restrict__ Wih2b,
    const float* __restrict__ bih2f, const float* __restrict__ bhh2f,
    const float* __restrict__ bih2b, const float* __restrict__ bhh2b,
    u16* __restrict__ W1cat, u16* __restrict__ WAcat,
    float* __restrict__ b1cat, float* __restrict__ b2cat)
{
  int gid = blockIdx.x * 256 + threadIdx.x;   // 1024*256 = 262144
  int j = gid >> 8, e = gid & 255;            // j = permuted column jp
  int dirj = j >> 9, u = (j >> 2) & 127, g = j & 3;
  int r = g*128 + u;                          // 0..511
  float w1 = dirj ? Wih1b[r*256 + e] : Wih1f[r*256 + e];
  float wa = dirj ? Wih2b[(long)r*512 + e] : Wih2f[(long)r*512 + e];  // cols 0..255
  W1cat[gid] = f2b(w1);
  WAcat[gid] = f2b(wa);
  if (e == 0){
    b1cat[j] = dirj ? (bih1b[r] + bhh1b[r]) : (bih1f[r] + bhh1f[r]);
    b2cat[j] = dirj ? (bih2b[r] + bhh2b[r]) : (bih2f[r] + bhh2f[r]);
  }
}

// ---------------- embedding gather (flat order == reshape(L,B,E)) ----------------
__global__ __launch_bounds__(256) void embed_gather(
    const int* __restrict__ sent, const float* __restrict__ emb, u16* __restrict__ X)
{
  int w = threadIdx.x >> 6, lane = threadIdx.x & 63;
  long i = (long)blockIdx.x * 4 + w;          // row of X, 0..65535
  int idx = sent[i];
  const float4* src = (const float4*)(emb + (long)idx * 256);
  float4 v = src[lane];
  u16x4 o; o[0] = f2b(v.x); o[1] = f2b(v.y); o[2] = f2b(v.z); o[3] = f2b(v.w);
  *(u16x4*)(X + i*256 + lane*4) = o;
}

// ---- bf16 MFMA GEMM, A[MxK] rm, Bperm[NxK] rm, +bias; writes G''[grp][l][thr][4] ----
// permuted col j: dirj=j>>9, u=(j>>2)&127, g=j&3
// u -> v=u>>4, quad=(u>>2)&3, tp=u&3; thr = v*64+quad*16+tp*4+(b&3)
// grp = dirj*16 + (b>>2); off = (grp<<21) + (l<<11) + thr*4 + g  (u16 units)
__global__ __launch_bounds__(256) void gemm_bt(
    const u16* __restrict__ A, const u16* __restrict__ Bm,
    const float* __restrict__ bias, u16* __restrict__ Gp,
    int M, int N, int K)
{
  __shared__ __align__(16) u16 As[128*64];
  __shared__ __align__(16) u16 Bs[128*64];
  int tid = threadIdx.x;
  int w = tid >> 6, lane = tid & 63;
  int lq = lane & 15, quad = lane >> 4;
  int wm = w & 1, wn = w >> 1;
  long m0 = (long)blockIdx.x * 128;
  int n0 = blockIdx.y * 128;
  v4f acc[4][4];
  v4f zero = {0.f, 0.f, 0.f, 0.f};
#pragma unroll
  for (int i=0;i<4;i++)
#pragma unroll
    for (int j=0;j<4;j++) acc[i][j] = zero;

  for (int k0 = 0; k0 < K; k0 += 64){
#pragma unroll
    for (int c = 0; c < 4; c++){
      int lin = c*256 + tid;
      int row = lin >> 3, chunk = lin & 7;            // 128 rows x 8 chunks(16B)
      u16x8 av = *(const u16x8*)(A + (m0+row)*K + k0 + chunk*8);
      u16x8 bv = *(const u16x8*)(Bm + ((long)(n0+row))*K + k0 + chunk*8);
      int sw = chunk ^ (row & 7);                     // XOR swizzle vs bank conflicts
      *(u16x8*)(As + row*64 + sw*8) = av;
      *(u16x8*)(Bs + row*64 + sw*8) = bv;
    }
    __syncthreads();
#pragma unroll
    for (int s = 0; s < 2; s++){
      v8bf af[4], bf_[4];
#pragma unroll
      for (int i=0;i<4;i++){
        int row = wm*64 + i*16 + lq;
        int ch  = (s*4 + quad) ^ (row & 7);
        af[i] = __builtin_bit_cast(v8bf, *(const u16x8*)(As + row*64 + ch*8));
      }
#pragma unroll
      for (int j=0;j<4;j++){
        int row = wn*64 + j*16 + lq;
        int ch  = (s*4 + quad) ^ (row & 7);
        bf_[j] = __builtin_bit_cast(v8bf, *(const u16x8*)(Bs + row*64 + ch*8));
      }
#pragma unroll
      for (int i=0;i<4;i++)
#pragma unroll
        for (int j=0;j<4;j++)
          acc[i][j] = __builtin_amdgcn_mfma_f32_16x16x32_bf16(af[i], bf_[j], acc[i][j], 0, 0, 0);
    }
    __syncthreads();
  }
#pragma unroll
  for (int jt=0;jt<4;jt++){
    int j = n0 + wn*64 + jt*16 + lq;          // permuted column
    float bv = bias[j];
    int dirj = j >> 9, u = (j >> 2) & 127, g = j & 3;
    int v_ = u >> 4, qd = (u >> 2) & 3, tp = u & 3;
    int thrP = v_*64 + qd*16 + tp*4;
#pragma unroll
    for (int i16=0;i16<4;i16++){
#pragma unroll
      for (int r2=0;r2<4;r2++){
        long i = m0 + wm*64 + i16*16 + quad*4 + r2;
        int bb = (int)(i & 63); long l = i >> 6;
        long off = ((long)(dirj*16 + (bb>>2)) << 21) + (l << 11)
                 + (long)(thrP + (bb&3))*4 + g;
        Gp[off] = f2b(acc[i16][jt][r2] + bv);
      }
    }
  }
}

// ---------------- persistent BiLSTM layer: 32 WGs x 512 thr (2 dirs x 16 bgroups) ----
// Wave v (0..7): A tiles tau=0..3, tile row m = gate(m&3) of unit v*16+tau+4*(m>>2).
// Lane (quad,lq): acc[tau][r] = gate r of (unit v*16+4*quad+tau, batch lq) [lq<4 real].
// Final cell of lane: tau'=lq>>2, b3=lq&3, U=v*16+4*quad+tau', batch=b0+b3.
// Redistribute via row_ror DPP: lane b3+4*tau' <- lane b3's acc[tau'].
// G'': [grp][l][tid][4] bf16 (grp = dir*16+bg). Y: [l*64+b][256] (dir at col d*128).
__global__ __launch_bounds__(512, 2) void lstm_layer(
    const u16* __restrict__ G, const float* __restrict__ WhhF, const float* __restrict__ WhhB,
    const float* __restrict__ h0, const float* __restrict__ c0,
    const float* __restrict__ sT, const float* __restrict__ proj,
    u16* __restrict__ Y, float* __restrict__ catOut)
{
  int blk = blockIdx.x;
  int dir = blk >> 4, bg = blk & 15, b0 = bg * 4;
  int tid = threadIdx.x, v = tid >> 6, lane = tid & 63;
  int quad = lane >> 4, lq = lane & 15;
  int b3 = lq & 3, tp = lq >> 2;
  int U = v*16 + 4*quad + tp;                 // this thread's hidden unit
  int batch = b0 + b3;
  const float* Whh = dir ? WhhB : WhhF;

  __shared__ __align__(16) u16 hbuf[2][512];  // h[4 batches][128 units], chunk^batch swizzle

  // A-frags: lane holds A[m=lq][k=ks*32+quad*8+j]
  // tile tau row m: gate = m&3, unit = v*16 + tau + 4*(m>>2)
  v8bf Af[4][4];
  {
    int gate = lq & 3;
    int ur = v*16 + 4*(lq>>2);
#pragma unroll
    for (int tau=0;tau<4;tau++){
      const float* wr = Whh + (long)(gate*128 + ur + tau)*128;
#pragma unroll
      for (int ks=0;ks<4;ks++){
        u16x8 tmp;
#pragma unroll
        for (int jj=0;jj<8;jj++) tmp[jj] = f2b(wr[ks*32 + quad*8 + jj]);
        Af[tau][ks] = __builtin_bit_cast(v8bf, tmp);
      }
    }
  }

  // LDS offsets (u16): row = batch (128 u16), 16 chunks of 8, chunk ^ batch swizzle
  int wOff = b3*128 + (((U>>3) ^ b3) * 8) + (U & 7);
  int rOff[4];
#pragma unroll
  for (int ks=0;ks<4;ks++) rOff[ks] = lq*128 + (((ks*4 + quad) ^ lq) * 8);

  float cc = c0[dir*8192 + batch*128 + U];
  u16 h0b = f2b(h0[dir*8192 + batch*128 + U]);
  hbuf[0][wOff] = h0b;

  // attention fold (LSTM2): pr[g] = 64*proj[batch, dir*512 + g*128 + U]
  bool att = (proj != nullptr);
  float pr[4];
  if (att){
#pragma unroll
    for (int g=0;g<4;g++)
      pr[g] = 64.0f * proj[(long)batch*1024 + dir*512 + g*128 + U];
  }

  const u16x4* Gpb = (const u16x4*)(G + ((size_t)blk << 21)) + tid;  // u16 base + 2M u16/grp
  long dl = dir ? -1 : 1;
  long l0 = dir ? 1023 : 0;
  u16x4 gbuf[2];
  gbuf[0] = Gpb[l0 << 9];
  gbuf[1] = Gpb[(l0 + dl) << 9];
  const u16x4* gpf = Gpb + ((l0 + 2*dl) << 9); // runs 2 past end: ws-internal, harmless
  u16* yp = Y + (l0*64 + batch)*256 + dir*128 + U;

  // softmax scalar, depth-2 prefetched (LSTM2 only)
  float sv[2] = {0.f, 0.f};
  const float* spf = nullptr;
  if (att){
    const float* sp0 = sT + l0*64 + batch;
    sv[0] = sp0[0];
    sv[1] = sp0[dl*64];
    spf = sp0 + 2*dl*64;                      // runs 2 past end: ws-internal, harmless
  }

  // deferred Y store: step t's h stored at top of step t+1.
  u16 hbPrev = h0b;
  u16* ypPrev = yp;

  u16x8 zz = {0,0,0,0,0,0,0,0};
  v8bf bh[4];
#pragma unroll
  for (int ks=0;ks<4;ks++) bh[ks] = __builtin_bit_cast(v8bf, zz);

  const float NL2E = -1.4426950408889634f;
  const float N2L2E = -2.8853900817779268f;
  v4f zero4 = {0.f, 0.f, 0.f, 0.f};
  __syncthreads();   // full barrier once before the loop (h0 writes + init)

#pragma unroll 2
  for (int it = 0; it < 1024; ++it){
    int slot = it & 1;
    // deferred Y store of previous step's h (first iter: h0 -> overwritten later)
    *ypPrev = hbPrev;
    // gates for this step
    float gc[4];
#pragma unroll
    for (int g=0; g<4; g++) gc[g] = b2f(gbuf[slot][g]);
    gbuf[slot] = *gpf;                        // prefetch it+2 (same parity slot)
    gpf += dl << 9;
    float s = 0.f;
    if (att){
      s = sv[slot];
      sv[slot] = *spf;
      spf += dl*64;
    }
    // h fragments (real cols 0..3 only; lanes lq>=4 keep zero frags)
    if (lq < 4){
#pragma unroll
      for (int ks=0;ks<4;ks++)
        bh[ks] = __builtin_bit_cast(v8bf, *(const u16x8*)(&hbuf[slot][rOff[ks]]));
    }
    // 4 independent MFMA chains (tau = 0..3)
    v4f a0 = zero4, a1 = zero4, a2 = zero4, a3 = zero4;
#pragma unroll
    for (int ks=0;ks<4;ks++){
      a0 = __builtin_amdgcn_mfma_f32_16x16x32_bf16(Af[0][ks], bh[ks], a0, 0,0,0);
      a1 = __builtin_amdgcn_mfma_f32_16x16x32_bf16(Af[1][ks], bh[ks], a1, 0,0,0);
      a2 = __builtin_amdgcn_mfma_f32_16x16x32_bf16(Af[2][ks], bh[ks], a2, 0,0,0);
      a3 = __builtin_amdgcn_mfma_f32_16x16x32_bf16(Af[3][ks], bh[ks], a3, 0,0,0);
    }

    // redistribute: lane b3+4*tau' takes acc[tau'] from lane b3 (within row of 16)
    float val[4];
#pragma unroll
    for (int r=0;r<4;r++){
      float x  = a0[r];
      float t1 = ror12(a1[r]);  x = (tp==1) ? t1 : x;
      float t2 = ror8 (a2[r]);  x = (tp==2) ? t2 : x;
      float t3 = ror4 (a3[r]);  x = (tp==3) ? t3 : x;
      val[r] = x + gc[r];
    }
    if (att){
#pragma unroll
      for (int r=0;r<4;r++) val[r] = fmaf(s, pr[r], val[r]);
    }

    float i_ = val[0], f_ = val[1], g_ = val[2], o_ = val[3];
    float ef = __builtin_amdgcn_exp2f(f_ * NL2E);
    float ei = __builtin_amdgcn_exp2f(i_ * NL2E);
    float eg = __builtin_amdgcn_exp2f(fminf(g_ * N2L2E, 115.0f));
    float sf = __builtin_amdgcn_rcpf(1.0f + ef);
    float pp = (1.0f - eg) * __builtin_amdgcn_rcpf((1.0f + ei) * (1.0f + eg));
    float c2 = fmaf(cc, sf, pp);
    cc = c2;
    float eo = __builtin_amdgcn_exp2f(o_ * NL2E);
    float ec = __builtin_amdgcn_exp2f(fminf(c2 * N2L2E, 115.0f));
    float hv = (1.0f - ec) * __builtin_amdgcn_rcpf((1.0f + eo) * (1.0f + ec));

    u16 hb = f2b(hv);
    hbuf[slot^1][wOff] = hb;
    hbPrev = hb;
    ypPrev = yp;
    yp += dl*16384;
    lds_only_barrier();
  }
  *ypPrev = hbPrev;                           // last step's h
  if (catOut)
    catOut[(long)batch*256 + dir*128 + U] = cc;
}

// ---------------- attention: e = fbout . catc, softmax over L, proj = catc @ Wih2[:,256:].T ----
// s written TRANSPOSED: sT[l*64 + b]. proj in ORIGINAL column order.
__global__ __launch_bounds__(256) void attn_kernel(
    const u16* __restrict__ y1, const float* __restrict__ catc,
    const float* __restrict__ Wih2f, const float* __restrict__ Wih2b,
    float* __restrict__ sT, float* __restrict__ proj)
{
  int b = blockIdx.x, t = threadIdx.x;
  __shared__ float catv[256];
  __shared__ float ev[1024];
  __shared__ float red[256];
  catv[t] = catc[b*256 + t];
  __syncthreads();
  float evl[4];
#pragma unroll
  for (int r2=0;r2<4;r2++){
    int l = t + r2*256;
    const u16x8* row = (const u16x8*)(y1 + ((long)l*64 + b)*256);
    float acc = 0.f;
    for (int f8=0; f8<32; f8++){
      u16x8 v = row[f8];
#pragma unroll
      for (int k=0;k<8;k++) acc += b2f(v[k]) * catv[f8*8+k];
    }
    ev[l] = acc; evl[r2] = acc;
  }
  float mx = fmaxf(fmaxf(evl[0],evl[1]), fmaxf(evl[2],evl[3]));
  red[t] = mx;
  __syncthreads();
  for (int s=128; s>0; s>>=1){ if (t < s) red[t] = fmaxf(red[t], red[t+s]); __syncthreads(); }
  float m = red[0];
  __syncthreads();
  float sum = 0.f;
#pragma unroll
  for (int r2=0;r2<4;r2++){
    int l = t + r2*256;
    float e = __expf(ev[l] - m);
    ev[l] = e; sum += e;
  }
  red[t] = sum;
  __syncthreads();
  for (int s=128; s>0; s>>=1){ if (t < s) red[t] += red[t+s]; __syncthreads(); }
  float rz = __builtin_amdgcn_rcpf(red[0]);
#pragma unroll
  for (int r2=0;r2<4;r2++){
    int l = t + r2*256;
    sT[(long)l*64 + b] = ev[l] * rz;
  }
#pragma unroll
  for (int r2=0;r2<4;r2++){
    int j = t + r2*256;
    const float* wr = (j < 512) ? (Wih2f + (long)j*512 + 256)
                                : (Wih2b + (long)(j-512)*512 + 256);
    const float4* w4 = (const float4*)wr;
    float acc = 0.f;
#pragma unroll 8
    for (int f4=0; f4<64; f4++){
      float4 v = w4[f4];
      acc += v.x*catv[f4*4+0] + v.y*catv[f4*4+1] + v.z*catv[f4*4+2] + v.w*catv[f4*4+3];
    }
    proj[b*1024 + j] = acc;
  }
}

// ---------------- feats = out2 @ Wout.T + bout ----------------
__global__ __launch_bounds__(256) void featk(const u16* __restrict__ y2,
    const float* __restrict__ Wout, const float* __restrict__ bout, float* __restrict__ feats)
{
  __shared__ float wlds[1280];
  int t = threadIdx.x;
  for (int k=t;k<1280;k+=256) wlds[k] = Wout[k];
  __syncthreads();
  long i = (long)blockIdx.x*256 + t;
  const u16x8* row = (const u16x8*)(y2 + i*256);
  float acc[5] = {0.f,0.f,0.f,0.f,0.f};
  for (int f8=0; f8<32; f8++){
    u16x8 v = row[f8];
#pragma unroll
    for (int k=0;k<8;k++){
      float x = b2f(v[k]);
      int f = f8*8 + k;
#pragma unroll
      for (int c=0;c<5;c++) acc[c] += x * wlds[c*256 + f];
    }
  }
#pragma unroll
  for (int c=0;c<5;c++) feats[i*5 + c] = acc[c] + bout[c];
}

// ---------------- CRF forward, exp domain: sc[c] = M + ln E[c] ----------------
__global__ void crf_kernel(const float* __restrict__ feats, const float* __restrict__ masks,
                           const float* __restrict__ trans, float* __restrict__ out)
{
  int b = threadIdx.x;  // 64
  float etr[5][5], tr4[5];
#pragma unroll
  for (int c=0;c<5;c++)
#pragma unroll
    for (int cp=0;cp<5;cp++) etr[c][cp] = __expf(trans[c*5+cp]);  // e^-10000 -> 0
#pragma unroll
  for (int cp=0;cp<5;cp++) tr4[cp] = trans[4*5+cp];   // STOP row
  float E[5] = {0.f, 0.f, 0.f, 1.f, 0.f};             // exp(sc), START=3
  float M = 0.f;
  const float* fpB = feats + (long)b*5120;
  float ftn[5], mtn;
#pragma unroll
  for (int c=0;c<5;c++) ftn[c] = fpB[c];
  mtn = masks[b*1024];
  for (int l=0;l<1024;l++){
    float ft[5]; float mt = mtn;
#pragma unroll
    for (int c=0;c<5;c++) ft[c] = ftn[c];
    if (l < 1023){
      const float* fp = fpB + (l + 1)*5;
#pragma unroll
      for (int c=0;c<5;c++) ftn[c] = fp[c];
      mtn = masks[b*1024 + l + 1];
    }
    float En[5];
#pragma unroll
    for (int c=0;c<5;c++){
      float S = E[0]*etr[c][0];
#pragma unroll
      for (int cp=1;cp<5;cp++) S = fmaf(E[cp], etr[c][cp], S);
      En[c] = S * __expf(ft[c]);
    }
    bool take = (mt > 0.5f);
#pragma unroll
    for (int c=0;c<5;c++) E[c] = take ? En[c] : E[c];
    // exact power-of-2 renorm
    float mx = fmaxf(fmaxf(fmaxf(E[0],E[1]), fmaxf(E[2],E[3])), E[4]);
    int k = (int)((__builtin_bit_cast(unsigned, mx) >> 23) & 0xFFu) - 127;
    float s = __builtin_bit_cast(float, (unsigned)(127 - k) << 23);
#pragma unroll
    for (int c=0;c<5;c++) E[c] *= s;
    M = fmaf((float)k, 0.6931471805599453f, M);
  }
  float Sf = 0.f;
#pragma unroll
  for (int cp=0;cp<5;cp++) Sf = fmaf(E[cp], __expf(tr4[cp]), Sf);
  out[b] = M + __logf(Sf);
}

// ---------------- launcher ----------------
extern "C" void kernel_launch(void* const* d_in, const int* in_sizes, int n_in,
                              void* d_out, int out_size, void* d_ws, size_t ws_size,
                              hipStream_t stream)
{
  const int*   sent  = (const int*)  d_in[0];
  const float* masks = (const float*)d_in[1];
  const float* emb   = (const float*)d_in[2];
  const float* Wih1f = (const float*)d_in[3];
  const float* Whh1f = (const float*)d_in[4];
  const float* bih1f = (const float*)d_in[5];
  const float* bhh1f = (const float*)d_in[6];
  const float* Wih1b = (const float*)d_in[7];
  const float* Whh1b = (const float*)d_in[8];
  const float* bih1b = (const float*)d_in[9];
  const float* bhh1b = (const float*)d_in[10];
  const float* Wih2f = (const float*)d_in[11];
  const float* Whh2f = (const float*)d_in[12];
  const float* bih2f = (const float*)d_in[13];
  const float* bhh2f = (const float*)d_in[14];
  const float* Wih2b = (const float*)d_in[15];
  const float* Whh2b = (const float*)d_in[16];
  const float* bih2b = (const float*)d_in[17];
  const float* bhh2b = (const float*)d_in[18];
  const float* Wout  = (const float*)d_in[19];
  const float* bout  = (const float*)d_in[20];
  const float* trans = (const float*)d_in[21];
  const float* h0    = (const float*)d_in[22];
  const float* c0    = (const float*)d_in[23];
  const float* h02   = (const float*)d_in[24];
  const float* c02   = (const float*)d_in[25];
  float* out = (float*)d_out;

  // workspace layout (aliased: X/y1/y2 share, G per layer shares). ~170.7 MB.
  char* ws = (char*)d_ws;
  u16*   Ybuf  = (u16*)(ws + 0);              // 33,554,432 B: X, then y1, then y2
  u16*   Gbuf  = (u16*)(ws + 33554432);       // 134,217,728 B: G'' per layer (128 MB used)
  u16*   W1cat = (u16*)(ws + 167772160);      // 524,288 B (permuted cols, g fastest)
  u16*   WAcat = (u16*)(ws + 168296448);      // 524,288 B (permuted cols, g fastest)
  float* b1cat = (float*)(ws + 168820736);    // 4,096 B (permuted)
  float* b2cat = (float*)(ws + 168824832);    // 4,096 B (permuted)
  float* catcb = (float*)(ws + 168828928);    // 65,536 B
  float* sbuf  = (float*)(ws + 168894464);    // 262,144 B  (sT[l][64])
  float* projb = (float*)(ws + 169156608);    // 262,144 B (original col order)
  float* featb = (float*)(ws + 169418752);    // 1,310,720 B

  conv_weights<<<1024, 256, 0, stream>>>(Wih1f, Wih1b, bih1f, bhh1f, bih1b, bhh1b,
                                         Wih2f, Wih2b, bih2f, bhh2f, bih2b, bhh2b,
                                         W1cat, WAcat, b1cat, b2cat);
  embed_gather<<<16384, 256, 0, stream>>>(sent, emb, Ybuf);
  gemm_bt<<<dim3(512, 8), 256, 0, stream>>>(Ybuf, W1cat, b1cat, Gbuf, 65536, 1024, 256);
  lstm_layer<<<32, 512, 0, stream>>>(Gbuf, Whh1f, Whh1b, h0, c0, nullptr, nullptr, Ybuf, catcb);
  attn_kernel<<<64, 256, 0, stream>>>(Ybuf, catcb, Wih2f, Wih2b, sbuf, projb);
  gemm_bt<<<dim3(512, 8), 256, 0, stream>>>(Ybuf, WAcat, b2cat, Gbuf, 65536, 1024, 256);
  lstm_layer<<<32, 512, 0, stream>>>(Gbuf, Whh2f, Whh2b, h02, c02, sbuf, projb, Ybuf, nullptr);
  featk<<<256, 256, 0, stream>>>(Ybuf, Wout, bout, featb);
  crf_kernel<<<1, 64, 0, stream>>>(featb, masks, trans, out);
}

// Round 13
// 1733.287 us; speedup vs baseline: 1.3566x; 1.0040x over previous
//
#include <hip/hip_runtime.h>
#include <hip/hip_bf16.h>

// BiLSTM-CRF forward. B=64, L=1024, E=256, H=128 (per dir), C=5, V=32000.
// R12: R11 + LSTM VALU-issue shave: (1) G/sT/Y addressed as uniform SGPR-stepped
// base + fixed per-thread voffset (no per-thread 64-bit pointer bumps);
// (2) LDS B-frag reads unconditional from row lq&3 (broadcast; D cols 4-15
// become copies of 0-3, never consumed) -> no divergent branch, no zero-init.

typedef unsigned short u16;
typedef unsigned int u32;
typedef __bf16 v8bf __attribute__((ext_vector_type(8)));
typedef float  v4f  __attribute__((ext_vector_type(4)));
typedef unsigned short u16x8 __attribute__((ext_vector_type(8)));
typedef unsigned short u16x4 __attribute__((ext_vector_type(4)));

__device__ __forceinline__ float b2f(u16 b){
  return __builtin_bit_cast(float, ((unsigned)b) << 16);
}
__device__ __forceinline__ u16 f2b(float x){           // RNE f32->bf16
  unsigned u = __builtin_bit_cast(unsigned, x);
  unsigned r = (u + 0x7FFFu + ((u >> 16) & 1u)) >> 16;
  return (u16)r;
}
// dst[i] = src[(i+N)&15] within each row of 16 lanes
__device__ __forceinline__ float ror4(float x){
  return __builtin_bit_cast(float, __builtin_amdgcn_mov_dpp(
      __builtin_bit_cast(int, x), 0x124, 0xF, 0xF, true));
}
__device__ __forceinline__ float ror8(float x){
  return __builtin_bit_cast(float, __builtin_amdgcn_mov_dpp(
      __builtin_bit_cast(int, x), 0x128, 0xF, 0xF, true));
}
__device__ __forceinline__ float ror12(float x){
  return __builtin_bit_cast(float, __builtin_amdgcn_mov_dpp(
      __builtin_bit_cast(int, x), 0x12C, 0xF, 0xF, true));
}
// LDS-only workgroup barrier
__device__ __forceinline__ void lds_only_barrier(){
  __builtin_amdgcn_fence(__ATOMIC_RELEASE, "workgroup", "local");
  __builtin_amdgcn_s_barrier();
  __builtin_amdgcn_fence(__ATOMIC_ACQUIRE, "workgroup", "local");
}

// ---------------- weight prep: permuted concat + fp32->bf16 ----------------
// permuted col jp: dirj=jp>>9, u=(jp>>2)&127, g=jp&3; original row r = g*128+u
__global__ __launch_bounds__(256) void conv_weights(
    const float* __restrict__ Wih1f, const float* __restrict__ Wih1b,
    const float* __restrict__ bih1f, const float* __restrict__ bhh1f,
    const float* __restrict__ bih1b, const float* __restrict__ bhh1b,
    const float* __restrict__ Wih2f, const float* __restrict__ Wih2b,
    const float* __restrict__ bih2f, const float* __restrict__ bhh2f,
    const float* __restrict__ bih2b, const float* __restrict__ bhh2b,
    u16* __restrict__ W1cat, u16* __restrict__ WAcat,
    float* __restrict__ b1cat, float* __restrict__ b2cat)
{
  int gid = blockIdx.x * 256 + threadIdx.x;   // 1024*256 = 262144
  int j = gid >> 8, e = gid & 255;            // j = permuted column jp
  int dirj = j >> 9, u = (j >> 2) & 127, g = j & 3;
  int r = g*128 + u;                          // 0..511
  float w1 = dirj ? Wih1b[r*256 + e] : Wih1f[r*256 + e];
  float wa = dirj ? Wih2b[(long)r*512 + e] : Wih2f[(long)r*512 + e];  // cols 0..255
  W1cat[gid] = f2b(w1);
  WAcat[gid] = f2b(wa);
  if (e == 0){
    b1cat[j] = dirj ? (bih1b[r] + bhh1b[r]) : (bih1f[r] + bhh1f[r]);
    b2cat[j] = dirj ? (bih2b[r] + bhh2b[r]) : (bih2f[r] + bhh2f[r]);
  }
}

// ---------------- embedding gather (flat order == reshape(L,B,E)) ----------------
__global__ __launch_bounds__(256) void embed_gather(
    const int* __restrict__ sent, const float* __restrict__ emb, u16* __restrict__ X)
{
  int w = threadIdx.x >> 6, lane = threadIdx.x & 63;
  long i = (long)blockIdx.x * 4 + w;          // row of X, 0..65535
  int idx = sent[i];
  const float4* src = (const float4*)(emb + (long)idx * 256);
  float4 v = src[lane];
  u16x4 o; o[0] = f2b(v.x); o[1] = f2b(v.y); o[2] = f2b(v.z); o[3] = f2b(v.w);
  *(u16x4*)(X + i*256 + lane*4) = o;
}

// ---- bf16 MFMA GEMM, A[MxK] rm, Bperm[NxK] rm, +bias; writes G''[grp][l][thr][4] ----
// permuted col j: dirj=j>>9, u=(j>>2)&127, g=j&3
// u -> v=u>>4, quad=(u>>2)&3, tp=u&3; thr = v*64+quad*16+tp*4+(b&3)
// grp = dirj*16 + (b>>2); off = (grp<<21) + (l<<11) + thr*4 + g  (u16 units)
__global__ __launch_bounds__(256) void gemm_bt(
    const u16* __restrict__ A, const u16* __restrict__ Bm,
    const float* __restrict__ bias, u16* __restrict__ Gp,
    int M, int N, int K)
{
  __shared__ __align__(16) u16 As[128*64];
  __shared__ __align__(16) u16 Bs[128*64];
  int tid = threadIdx.x;
  int w = tid >> 6, lane = tid & 63;
  int lq = lane & 15, quad = lane >> 4;
  int wm = w & 1, wn = w >> 1;
  long m0 = (long)blockIdx.x * 128;
  int n0 = blockIdx.y * 128;
  v4f acc[4][4];
  v4f zero = {0.f, 0.f, 0.f, 0.f};
#pragma unroll
  for (int i=0;i<4;i++)
#pragma unroll
    for (int j=0;j<4;j++) acc[i][j] = zero;

  for (int k0 = 0; k0 < K; k0 += 64){
#pragma unroll
    for (int c = 0; c < 4; c++){
      int lin = c*256 + tid;
      int row = lin >> 3, chunk = lin & 7;            // 128 rows x 8 chunks(16B)
      u16x8 av = *(const u16x8*)(A + (m0+row)*K + k0 + chunk*8);
      u16x8 bv = *(const u16x8*)(Bm + ((long)(n0+row))*K + k0 + chunk*8);
      int sw = chunk ^ (row & 7);                     // XOR swizzle vs bank conflicts
      *(u16x8*)(As + row*64 + sw*8) = av;
      *(u16x8*)(Bs + row*64 + sw*8) = bv;
    }
    __syncthreads();
#pragma unroll
    for (int s = 0; s < 2; s++){
      v8bf af[4], bf_[4];
#pragma unroll
      for (int i=0;i<4;i++){
        int row = wm*64 + i*16 + lq;
        int ch  = (s*4 + quad) ^ (row & 7);
        af[i] = __builtin_bit_cast(v8bf, *(const u16x8*)(As + row*64 + ch*8));
      }
#pragma unroll
      for (int j=0;j<4;j++){
        int row = wn*64 + j*16 + lq;
        int ch  = (s*4 + quad) ^ (row & 7);
        bf_[j] = __builtin_bit_cast(v8bf, *(const u16x8*)(Bs + row*64 + ch*8));
      }
#pragma unroll
      for (int i=0;i<4;i++)
#pragma unroll
        for (int j=0;j<4;j++)
          acc[i][j] = __builtin_amdgcn_mfma_f32_16x16x32_bf16(af[i], bf_[j], acc[i][j], 0, 0, 0);
    }
    __syncthreads();
  }
#pragma unroll
  for (int jt=0;jt<4;jt++){
    int j = n0 + wn*64 + jt*16 + lq;          // permuted column
    float bv = bias[j];
    int dirj = j >> 9, u = (j >> 2) & 127, g = j & 3;
    int v_ = u >> 4, qd = (u >> 2) & 3, tp = u & 3;
    int thrP = v_*64 + qd*16 + tp*4;
#pragma unroll
    for (int i16=0;i16<4;i16++){
#pragma unroll
      for (int r2=0;r2<4;r2++){
        long i = m0 + wm*64 + i16*16 + quad*4 + r2;
        int bb = (int)(i & 63); long l = i >> 6;
        long off = ((long)(dirj*16 + (bb>>2)) << 21) + (l << 11)
                 + (long)(thrP + (bb&3))*4 + g;
        Gp[off] = f2b(acc[i16][jt][r2] + bv);
      }
    }
  }
}

// ---------------- persistent BiLSTM layer: 32 WGs x 512 thr (2 dirs x 16 bgroups) ----
// Wave v (0..7): A tiles tau=0..3, tile row m = gate(m&3) of unit v*16+tau+4*(m>>2).
// B cols: ALL 16 cols carry h[batch lq&3] (broadcast) -> D cols 4-15 are copies of
// cols 0-3; redistribution only consumes cols 0-3, so copies are harmless.
// Lane b3+4*tau' takes acc[tau'] from lane b3 via row_ror DPP -> 1 cell per lane.
// G'': [grp][l][tid][4] bf16 (grp = dir*16+bg). Uniform SGPR-stepped addressing.
__global__ __launch_bounds__(512, 2) void lstm_layer(
    const u16* __restrict__ G, const float* __restrict__ WhhF, const float* __restrict__ WhhB,
    const float* __restrict__ h0, const float* __restrict__ c0,
    const float* __restrict__ sT, const float* __restrict__ proj,
    u16* __restrict__ Y, float* __restrict__ catOut)
{
  int blk = blockIdx.x;
  int dir = blk >> 4, bg = blk & 15, b0 = bg * 4;
  int tid = threadIdx.x, v = tid >> 6, lane = tid & 63;
  int quad = lane >> 4, lq = lane & 15;
  int b3 = lq & 3, tp = lq >> 2;
  int U = v*16 + 4*quad + tp;                 // this thread's hidden unit
  int batch = b0 + b3;
  const float* Whh = dir ? WhhB : WhhF;

  __shared__ __align__(16) u16 hbuf[2][512];  // h[4 batches][128 units], chunk^batch swizzle

  // A-frags: lane holds A[m=lq][k=ks*32+quad*8+j]
  // tile tau row m: gate = m&3, unit = v*16 + tau + 4*(m>>2)
  v8bf Af[4][4];
  {
    int gate = lq & 3;
    int ur = v*16 + 4*(lq>>2);
#pragma unroll
    for (int tau=0;tau<4;tau++){
      const float* wr = Whh + (long)(gate*128 + ur + tau)*128;
#pragma unroll
      for (int ks=0;ks<4;ks++){
        u16x8 tmp;
#pragma unroll
        for (int jj=0;jj<8;jj++) tmp[jj] = f2b(wr[ks*32 + quad*8 + jj]);
        Af[tau][ks] = __builtin_bit_cast(v8bf, tmp);
      }
    }
  }

  // LDS offsets (u16): read row lq&3 (broadcast across tau groups), write own cell
  int wOff = b3*128 + (((U>>3) ^ b3) * 8) + (U & 7);
  int rOff[4];
#pragma unroll
  for (int ks=0;ks<4;ks++) rOff[ks] = b3*128 + (((ks*4 + quad) ^ b3) * 8);

  float cc = c0[dir*8192 + batch*128 + U];
  u16 h0b = f2b(h0[dir*8192 + batch*128 + U]);
  hbuf[0][wOff] = h0b;

  // attention fold (LSTM2): pr[g] = 64*proj[batch, dir*512 + g*128 + U]
  bool att = (proj != nullptr);
  float pr[4];
  if (att){
#pragma unroll
    for (int g=0;g<4;g++)
      pr[g] = 64.0f * proj[(long)batch*1024 + dir*512 + g*128 + U];
  }

  // uniform bases + fixed per-thread offsets (compiler: SGPR base, VGPR voffset)
  const u16* GbU = G + ((size_t)blk << 21);   // uniform
  int gvo = tid * 4;                          // fixed per-thread, u16 units
  int yvo = batch*256 + dir*128 + U;          // fixed per-thread
  long dl = dir ? -1 : 1;
  long l0 = dir ? 1023 : 0;

  u16x4 gbuf[2];
  gbuf[0] = *(const u16x4*)(GbU + ((size_t)l0 << 11) + gvo);
  gbuf[1] = *(const u16x4*)(GbU + ((size_t)(l0 + dl) << 11) + gvo);
  long lpf = l0 + 2*dl;                       // prefetch index (runs 2 past end: ws-internal)
  long lcur = l0;                             // current step index

  // softmax scalar, depth-2 prefetched (LSTM2 only)
  float sv[2] = {0.f, 0.f};
  if (att){
    sv[0] = sT[l0*64 + batch];
    sv[1] = sT[(l0 + dl)*64 + batch];
  }

  // deferred Y store: step t's h stored at top of step t+1.
  u16 hbPrev = h0b;
  long lprev = l0;

  const float NL2E = -1.4426950408889634f;
  const float N2L2E = -2.8853900817779268f;
  v4f zero4 = {0.f, 0.f, 0.f, 0.f};
  __syncthreads();   // full barrier once before the loop (h0 writes + init)

#pragma unroll 2
  for (int it = 0; it < 1024; ++it){
    int slot = it & 1;
    // deferred Y store of previous step's h (first iter: h0 -> overwritten later)
    Y[lprev*16384 + yvo] = hbPrev;
    // gates for this step
    float gc[4];
#pragma unroll
    for (int g=0; g<4; g++) gc[g] = b2f(gbuf[slot][g]);
    gbuf[slot] = *(const u16x4*)(GbU + ((size_t)lpf << 11) + gvo);  // prefetch it+2
    float s = 0.f;
    if (att){
      s = sv[slot];
      sv[slot] = sT[lpf*64 + batch];
    }
    lpf += dl;
    // h fragments: all lanes read row lq&3 (broadcast); cols 4-15 become copies
    v8bf bh[4];
#pragma unroll
    for (int ks=0;ks<4;ks++)
      bh[ks] = __builtin_bit_cast(v8bf, *(const u16x8*)(&hbuf[slot][rOff[ks]]));
    // 4 independent MFMA chains (tau = 0..3)
    v4f a0 = zero4, a1 = zero4, a2 = zero4, a3 = zero4;
#pragma unroll
    for (int ks=0;ks<4;ks++){
      a0 = __builtin_amdgcn_mfma_f32_16x16x32_bf16(Af[0][ks], bh[ks], a0, 0,0,0);
      a1 = __builtin_amdgcn_mfma_f32_16x16x32_bf16(Af[1][ks], bh[ks], a1, 0,0,0);
      a2 = __builtin_amdgcn_mfma_f32_16x16x32_bf16(Af[2][ks], bh[ks], a2, 0,0,0);
      a3 = __builtin_amdgcn_mfma_f32_16x16x32_bf16(Af[3][ks], bh[ks], a3, 0,0,0);
    }

    // redistribute: lane b3+4*tau' takes acc[tau'] from lane b3 (within row of 16)
    float val[4];
#pragma unroll
    for (int r=0;r<4;r++){
      float x  = a0[r];
      float t1 = ror12(a1[r]);  x = (tp==1) ? t1 : x;
      float t2 = ror8 (a2[r]);  x = (tp==2) ? t2 : x;
      float t3 = ror4 (a3[r]);  x = (tp==3) ? t3 : x;
      val[r] = x + gc[r];
    }
    if (att){
#pragma unroll
      for (int r=0;r<4;r++) val[r] = fmaf(s, pr[r], val[r]);
    }

    float i_ = val[0], f_ = val[1], g_ = val[2], o_ = val[3];
    float ef = __builtin_amdgcn_exp2f(f_ * NL2E);
    float ei = __builtin_amdgcn_exp2f(i_ * NL2E);
    float eg = __builtin_amdgcn_exp2f(fminf(g_ * N2L2E, 115.0f));
    float sf = __builtin_amdgcn_rcpf(1.0f + ef);
    float pp = (1.0f - eg) * __builtin_amdgcn_rcpf((1.0f + ei) * (1.0f + eg));
    float c2 = fmaf(cc, sf, pp);
    cc = c2;
    float eo = __builtin_amdgcn_exp2f(o_ * NL2E);
    float ec = __builtin_amdgcn_exp2f(fminf(c2 * N2L2E, 115.0f));
    float hv = (1.0f - ec) * __builtin_amdgcn_rcpf((1.0f + eo) * (1.0f + ec));

    u16 hb = f2b(hv);
    hbuf[slot^1][wOff] = hb;
    hbPrev = hb;
    lprev = lcur;
    lcur += dl;
    lds_only_barrier();
  }
  Y[lprev*16384 + yvo] = hbPrev;              // last step's h
  if (catOut)
    catOut[(long)batch*256 + dir*128 + U] = cc;
}

// ---------------- attention: e = fbout . catc, softmax over L, proj = catc @ Wih2[:,256:].T ----
// s written TRANSPOSED: sT[l*64 + b]. proj in ORIGINAL column order.
__global__ __launch_bounds__(256) void attn_kernel(
    const u16* __restrict__ y1, const float* __restrict__ catc,
    const float* __restrict__ Wih2f, const float* __restrict__ Wih2b,
    float* __restrict__ sT, float* __restrict__ proj)
{
  int b = blockIdx.x, t = threadIdx.x;
  __shared__ float catv[256];
  __shared__ float ev[1024];
  __shared__ float red[256];
  catv[t] = catc[b*256 + t];
  __syncthreads();
  float evl[4];
#pragma unroll
  for (int r2=0;r2<4;r2++){
    int l = t + r2*256;
    const u16x8* row = (const u16x8*)(y1 + ((long)l*64 + b)*256);
    float acc = 0.f;
    for (int f8=0; f8<32; f8++){
      u16x8 v = row[f8];
#pragma unroll
      for (int k=0;k<8;k++) acc += b2f(v[k]) * catv[f8*8+k];
    }
    ev[l] = acc; evl[r2] = acc;
  }
  float mx = fmaxf(fmaxf(evl[0],evl[1]), fmaxf(evl[2],evl[3]));
  red[t] = mx;
  __syncthreads();
  for (int s=128; s>0; s>>=1){ if (t < s) red[t] = fmaxf(red[t], red[t+s]); __syncthreads(); }
  float m = red[0];
  __syncthreads();
  float sum = 0.f;
#pragma unroll
  for (int r2=0;r2<4;r2++){
    int l = t + r2*256;
    float e = __expf(ev[l] - m);
    ev[l] = e; sum += e;
  }
  red[t] = sum;
  __syncthreads();
  for (int s=128; s>0; s>>=1){ if (t < s) red[t] += red[t+s]; __syncthreads(); }
  float rz = __builtin_amdgcn_rcpf(red[0]);
#pragma unroll
  for (int r2=0;r2<4;r2++){
    int l = t + r2*256;
    sT[(long)l*64 + b] = ev[l] * rz;
  }
#pragma unroll
  for (int r2=0;r2<4;r2++){
    int j = t + r2*256;
    const float* wr = (j < 512) ? (Wih2f + (long)j*512 + 256)
                                : (Wih2b + (long)(j-512)*512 + 256);
    const float4* w4 = (const float4*)wr;
    float acc = 0.f;
#pragma unroll 8
    for (int f4=0; f4<64; f4++){
      float4 v = w4[f4];
      acc += v.x*catv[f4*4+0] + v.y*catv[f4*4+1] + v.z*catv[f4*4+2] + v.w*catv[f4*4+3];
    }
    proj[b*1024 + j] = acc;
  }
}

// ---------------- feats = out2 @ Wout.T + bout ----------------
__global__ __launch_bounds__(256) void featk(const u16* __restrict__ y2,
    const float* __restrict__ Wout, const float* __restrict__ bout, float* __restrict__ feats)
{
  __shared__ float wlds[1280];
  int t = threadIdx.x;
  for (int k=t;k<1280;k+=256) wlds[k] = Wout[k];
  __syncthreads();
  long i = (long)blockIdx.x*256 + t;
  const u16x8* row = (const u16x8*)(y2 + i*256);
  float acc[5] = {0.f,0.f,0.f,0.f,0.f};
  for (int f8=0; f8<32; f8++){
    u16x8 v = row[f8];
#pragma unroll
    for (int k=0;k<8;k++){
      float x = b2f(v[k]);
      int f = f8*8 + k;
#pragma unroll
      for (int c=0;c<5;c++) acc[c] += x * wlds[c*256 + f];
    }
  }
#pragma unroll
  for (int c=0;c<5;c++) feats[i*5 + c] = acc[c] + bout[c];
}

// ---------------- CRF forward, exp domain: sc[c] = M + ln E[c] ----------------
__global__ void crf_kernel(const float* __restrict__ feats, const float* __restrict__ masks,
                           const float* __restrict__ trans, float* __restrict__ out)
{
  int b = threadIdx.x;  // 64
  float etr[5][5], tr4[5];
#pragma unroll
  for (int c=0;c<5;c++)
#pragma unroll
    for (int cp=0;cp<5;cp++) etr[c][cp] = __expf(trans[c*5+cp]);  // e^-10000 -> 0
#pragma unroll
  for (int cp=0;cp<5;cp++) tr4[cp] = trans[4*5+cp];   // STOP row
  float E[5] = {0.f, 0.f, 0.f, 1.f, 0.f};             // exp(sc), START=3
  float M = 0.f;
  const float* fpB = feats + (long)b*5120;
  float ftn[5], mtn;
#pragma unroll
  for (int c=0;c<5;c++) ftn[c] = fpB[c];
  mtn = masks[b*1024];
  for (int l=0;l<1024;l++){
    float ft[5]; float mt = mtn;
#pragma unroll
    for (int c=0;c<5;c++) ft[c] = ftn[c];
    if (l < 1023){
      const float* fp = fpB + (l + 1)*5;
#pragma unroll
      for (int c=0;c<5;c++) ftn[c] = fp[c];
      mtn = masks[b*1024 + l + 1];
    }
    float En[5];
#pragma unroll
    for (int c=0;c<5;c++){
      float S = E[0]*etr[c][0];
#pragma unroll
      for (int cp=1;cp<5;cp++) S = fmaf(E[cp], etr[c][cp], S);
      En[c] = S * __expf(ft[c]);
    }
    bool take = (mt > 0.5f);
#pragma unroll
    for (int c=0;c<5;c++) E[c] = take ? En[c] : E[c];
    // exact power-of-2 renorm
    float mx = fmaxf(fmaxf(fmaxf(E[0],E[1]), fmaxf(E[2],E[3])), E[4]);
    int k = (int)((__builtin_bit_cast(unsigned, mx) >> 23) & 0xFFu) - 127;
    float s = __builtin_bit_cast(float, (unsigned)(127 - k) << 23);
#pragma unroll
    for (int c=0;c<5;c++) E[c] *= s;
    M = fmaf((float)k, 0.6931471805599453f, M);
  }
  float Sf = 0.f;
#pragma unroll
  for (int cp=0;cp<5;cp++) Sf = fmaf(E[cp], __expf(tr4[cp]), Sf);
  out[b] = M + __logf(Sf);
}

// ---------------- launcher ----------------
extern "C" void kernel_launch(void* const* d_in, const int* in_sizes, int n_in,
                              void* d_out, int out_size, void* d_ws, size_t ws_size,
                              hipStream_t stream)
{
  const int*   sent  = (const int*)  d_in[0];
  const float* masks = (const float*)d_in[1];
  const float* emb   = (const float*)d_in[2];
  const float* Wih1f = (const float*)d_in[3];
  const float* Whh1f = (const float*)d_in[4];
  const float* bih1f = (const float*)d_in[5];
  const float* bhh1f = (const float*)d_in[6];
  const float* Wih1b = (const float*)d_in[7];
  const float* Whh1b = (const float*)d_in[8];
  const float* bih1b = (const float*)d_in[9];
  const float* bhh1b = (const float*)d_in[10];
  const float* Wih2f = (const float*)d_in[11];
  const float* Whh2f = (const float*)d_in[12];
  const float* bih2f = (const float*)d_in[13];
  const float* bhh2f = (const float*)d_in[14];
  const float* Wih2b = (const float*)d_in[15];
  const float* Whh2b = (const float*)d_in[16];
  const float* bih2b = (const float*)d_in[17];
  const float* bhh2b = (const float*)d_in[18];
  const float* Wout  = (const float*)d_in[19];
  const float* bout  = (const float*)d_in[20];
  const float* trans = (const float*)d_in[21];
  const float* h0    = (const float*)d_in[22];
  const float* c0    = (const float*)d_in[23];
  const float* h02   = (const float*)d_in[24];
  const float* c02   = (const float*)d_in[25];
  float* out = (float*)d_out;

  // workspace layout (aliased: X/y1/y2 share, G per layer shares). ~170.7 MB.
  char* ws = (char*)d_ws;
  u16*   Ybuf  = (u16*)(ws + 0);              // 33,554,432 B: X, then y1, then y2
  u16*   Gbuf  = (u16*)(ws + 33554432);       // 134,217,728 B: G'' per layer (128 MB used)
  u16*   W1cat = (u16*)(ws + 167772160);      // 524,288 B (permuted cols, g fastest)
  u16*   WAcat = (u16*)(ws + 168296448);      // 524,288 B (permuted cols, g fastest)
  float* b1cat = (float*)(ws + 168820736);    // 4,096 B (permuted)
  float* b2cat = (float*)(ws + 168824832);    // 4,096 B (permuted)
  float* catcb = (float*)(ws + 168828928);    // 65,536 B
  float* sbuf  = (float*)(ws + 168894464);    // 262,144 B  (sT[l][64])
  float* projb = (float*)(ws + 169156608);    // 262,144 B (original col order)
  float* featb = (float*)(ws + 169418752);    // 1,310,720 B

  conv_weights<<<1024, 256, 0, stream>>>(Wih1f, Wih1b, bih1f, bhh1f, bih1b, bhh1b,
                                         Wih2f, Wih2b, bih2f, bhh2f, bih2b, bhh2b,
                                         W1cat, WAcat, b1cat, b2cat);
  embed_gather<<<16384, 256, 0, stream>>>(sent, emb, Ybuf);
  gemm_bt<<<dim3(512, 8), 256, 0, stream>>>(Ybuf, W1cat, b1cat, Gbuf, 65536, 1024, 256);
  lstm_layer<<<32, 512, 0, stream>>>(Gbuf, Whh1f, Whh1b, h0, c0, nullptr, nullptr, Ybuf, catcb);
  attn_kernel<<<64, 256, 0, stream>>>(Ybuf, catcb, Wih2f, Wih2b, sbuf, projb);
  gemm_bt<<<dim3(512, 8), 256, 0, stream>>>(Ybuf, WAcat, b2cat, Gbuf, 65536, 1024, 256);
  lstm_layer<<<32, 512, 0, stream>>>(Gbuf, Whh2f, Whh2b, h02, c02, sbuf, projb, Ybuf, nullptr);
  featk<<<256, 256, 0, stream>>>(Ybuf, Wout, bout, featb);
  crf_kernel<<<1, 64, 0, stream>>>(featb, masks, trans, out);
}